// Round 6
// baseline (827.401 us; speedup 1.0000x reference)
//
#include <hip/hip_runtime.h>

#define HH   6
#define NN   343
#define BB   512
#define DIMC 192
#define MM   (BB*NN)      // 175616

// workspace offsets (bytes)
#define OFF_TABLE 0                        // [2197][8] f32
#define OFF_R     70400                    // [6][343][352] f32  (exp(rpb-26), zero tail)
#define OFF_MB    2968064                  // [64*343][16] u32   (bit-packed mask, lane-repacked)
#define OFF_QB    4372992                  // [M][192] bf16 (normalized * scale * log2e)
#define OFF_KB    (OFF_QB + 67436544)      // [M][192] bf16 (normalized)
#define OFF_VB    (OFF_KB + 67436544)
#define OFF_CROSS (OFF_VB + 67436544)
// end = 274,119,168 bytes

typedef __bf16 bf16x8 __attribute__((ext_vector_type(8)));
typedef float  f32x4  __attribute__((ext_vector_type(4)));

__device__ __forceinline__ f32x4 mfma16(bf16x8 a, bf16x8 b, f32x4 c) {
    return __builtin_amdgcn_mfma_f32_16x16x32_bf16(a, b, c, 0, 0, 0);
}

__device__ __forceinline__ unsigned pack2(float a, float b) {
    union { __bf16 h[2]; unsigned u; } x;
    x.h[0] = (__bf16)a; x.h[1] = (__bf16)b;
    return x.u;
}

// ---------------- K1: CPB MLP -> table[2197][8] ----------------
__global__ __launch_bounds__(256) void cpb_table_kernel(
    const float* __restrict__ rel_table, const float* __restrict__ w1,
    const float* __restrict__ b1, const float* __restrict__ w2,
    float* __restrict__ table)
{
    int i = blockIdx.x;
    int t = threadIdx.x;
    float t0 = rel_table[i*3+0], t1 = rel_table[i*3+1], t2 = rel_table[i*3+2];
    float acc[HH];
    #pragma unroll
    for (int h = 0; h < HH; h++) acc[h] = 0.f;
    for (int j = t; j < 512; j += 256) {
        float hv = w1[j*3+0]*t0 + w1[j*3+1]*t1 + w1[j*3+2]*t2 + b1[j];
        hv = fmaxf(hv, 0.f);
        #pragma unroll
        for (int h = 0; h < HH; h++) acc[h] += w2[h*512+j] * hv;
    }
    __shared__ float red[256*HH];
    #pragma unroll
    for (int h = 0; h < HH; h++) red[t*HH+h] = acc[h];
    __syncthreads();
    for (int s = 128; s > 0; s >>= 1) {
        if (t < s) {
            #pragma unroll
            for (int h = 0; h < HH; h++) red[t*HH+h] += red[(t+s)*HH+h];
        }
        __syncthreads();
    }
    if (t < HH) table[(size_t)i*8 + t] = red[t];
}

// ---------------- K2: R = exp(16*sigmoid(gather) - 26), [6][343][352] ----------------
__global__ __launch_bounds__(256) void r_kernel(
    const float* __restrict__ table, const int* __restrict__ rp_index,
    float* __restrict__ R)
{
    int id = blockIdx.x*256 + threadIdx.x;
    if (id >= HH*NN*352) return;
    int h   = id / (NN*352);
    int rem = id - h*(NN*352);
    int n   = rem / 352;
    int mc  = rem - n*352;
    float out = 0.f;
    if (mc < NN) {
        float v = table[(size_t)rp_index[n*NN+mc]*8 + h];
        float r = 16.f / (1.f + __expf(-v));
        out = __expf(r - 26.f);
    }
    R[id] = out;
}

// ---------------- K3: bit-pack mask, lane-stream layout ----------------
__global__ __launch_bounds__(256) void mbits_kernel(
    const float* __restrict__ mask, unsigned* __restrict__ mb)
{
    int id  = blockIdx.x*256 + threadIdx.x;   // 64*343*4 threads
    int lg  = id & 3;
    int row = id >> 2;                         // w*343 + n
    const float* mrow = mask + (size_t)row*NN;
    unsigned out[3];
    #pragma unroll
    for (int t = 0; t < 3; t++) {
        unsigned u = 0;
        #pragma unroll
        for (int bb = 0; bb < 32; bb++) {
            int mt = 8*t + (bb>>2), r = bb & 3;
            int m  = 16*mt + 4*lg + r;
            if (m < NN && mrow[m] > -50.f) u |= (1u << bb);
        }
        out[t] = u;
    }
    *(uint4*)(mb + (size_t)row*16 + 4*lg) = make_uint4(out[0], out[1], out[2], 0u);
}

// ---------------- GEMM: f32 in -> bf16 out, tile 64x192, K=192, up to 2 phases (LDS-staged) ----------------
// norm: 0 = none, 1 = k-norm (1/|k|), 2 = q-norm (scale*log2e/|q|)
__global__ __launch_bounds__(256) void gemm_f32in(
    const float* __restrict__ A, const float* __restrict__ ls,
    const float* __restrict__ W0, const float* __restrict__ bias0, int norm0, __bf16* __restrict__ D0,
    const float* __restrict__ W1, const float* __restrict__ bias1, int norm1, __bf16* __restrict__ D1)
{
    __shared__ __bf16 As[64][200];
    __shared__ __bf16 Ws[192][40];
    int m0 = blockIdx.x * 64;
    int t  = threadIdx.x;
    #pragma unroll
    for (int i = 0; i < 12; i++) {
        int f = t + 256*i;
        int row = f / 48, ch = (f - row*48) * 4;
        float4 v = *(const float4*)(A + (size_t)(m0+row)*DIMC + ch);
        __bf16* dst = &As[row][ch];
        dst[0] = (__bf16)v.x; dst[1] = (__bf16)v.y; dst[2] = (__bf16)v.z; dst[3] = (__bf16)v.w;
    }
    int wave = t >> 6, lane = t & 63, lr = lane & 15, lg = lane >> 4;
    for (int phase = 0; phase < 2; phase++) {
        const float* W    = phase ? W1 : W0;
        if (!W) break;
        const float* bias = phase ? bias1 : bias0;
        int          nrm  = phase ? norm1 : norm0;
        __bf16*      D    = phase ? D1 : D0;
        f32x4 acc[12];
        #pragma unroll
        for (int i = 0; i < 12; i++) acc[i] = (f32x4){0.f,0.f,0.f,0.f};
        for (int ks = 0; ks < 6; ks++) {
            __syncthreads();
            #pragma unroll
            for (int i = 0; i < 6; i++) {
                int f = t + 256*i;
                int row = f / 8, ch = (f - row*8) * 4;
                float4 v = *(const float4*)(W + (size_t)row*DIMC + ks*32 + ch);
                __bf16* dst = &Ws[row][ch];
                dst[0] = (__bf16)v.x; dst[1] = (__bf16)v.y; dst[2] = (__bf16)v.z; dst[3] = (__bf16)v.w;
            }
            __syncthreads();
            bf16x8 afrag = *(const bf16x8*)&As[16*wave + lr][ks*32 + 8*lg];
            #pragma unroll
            for (int ct = 0; ct < 12; ct++) {
                bf16x8 bfrag = *(const bf16x8*)&Ws[16*ct + lr][8*lg];
                acc[ct] = mfma16(afrag, bfrag, acc[ct]);
            }
        }
        if (bias) {
            #pragma unroll
            for (int ct = 0; ct < 12; ct++) {
                float bv = bias[16*ct + lr];
                #pragma unroll
                for (int reg = 0; reg < 4; reg++) acc[ct][reg] += bv;
            }
        }
        if (nrm) {
            #pragma unroll
            for (int h = 0; h < HH; h++) {
                float sc = 1.f;
                if (nrm == 2) sc = __expf(fminf(ls[h], 4.6051702f)) * 1.4426950408889634f;
                #pragma unroll
                for (int reg = 0; reg < 4; reg++) {
                    float ss = acc[2*h][reg]*acc[2*h][reg] + acc[2*h+1][reg]*acc[2*h+1][reg];
                    ss += __shfl_xor(ss, 1); ss += __shfl_xor(ss, 2);
                    ss += __shfl_xor(ss, 4); ss += __shfl_xor(ss, 8);
                    float f = sc / fmaxf(sqrtf(ss), 1e-12f);
                    acc[2*h][reg]   *= f;
                    acc[2*h+1][reg] *= f;
                }
            }
        }
        #pragma unroll
        for (int ct = 0; ct < 12; ct++) {
            int c = 16*ct + lr;
            #pragma unroll
            for (int reg = 0; reg < 4; reg++) {
                int r = m0 + 16*wave + 4*lg + reg;
                D[(size_t)r*DIMC + c] = (__bf16)acc[ct][reg];
            }
        }
    }
}

// ---------------- proj GEMM: bf16 in -> f32 out + bias (LDS-staged) ----------------
__global__ __launch_bounds__(256) void gemm_proj(
    const __bf16* __restrict__ A, const float* __restrict__ W,
    const float* __restrict__ bias, float* __restrict__ D)
{
    __shared__ __bf16 As[64][200];
    __shared__ __bf16 Ws[192][40];
    int m0 = blockIdx.x * 64;
    int t  = threadIdx.x;
    #pragma unroll
    for (int i = 0; i < 6; i++) {
        int f = t + 256*i;
        int row = f / 24, ch = (f - row*24) * 8;
        uint4 v = *(const uint4*)(A + (size_t)(m0+row)*DIMC + ch);
        *(uint4*)&As[row][ch] = v;
    }
    int wave = t >> 6, lane = t & 63, lr = lane & 15, lg = lane >> 4;
    f32x4 acc[12];
    #pragma unroll
    for (int i = 0; i < 12; i++) acc[i] = (f32x4){0.f,0.f,0.f,0.f};
    for (int ks = 0; ks < 6; ks++) {
        __syncthreads();
        #pragma unroll
        for (int i = 0; i < 6; i++) {
            int f = t + 256*i;
            int row = f / 8, ch = (f - row*8) * 4;
            float4 v = *(const float4*)(W + (size_t)row*DIMC + ks*32 + ch);
            __bf16* dst = &Ws[row][ch];
            dst[0] = (__bf16)v.x; dst[1] = (__bf16)v.y; dst[2] = (__bf16)v.z; dst[3] = (__bf16)v.w;
        }
        __syncthreads();
        bf16x8 afrag = *(const bf16x8*)&As[16*wave + lr][ks*32 + 8*lg];
        #pragma unroll
        for (int ct = 0; ct < 12; ct++) {
            bf16x8 bfrag = *(const bf16x8*)&Ws[16*ct + lr][8*lg];
            acc[ct] = mfma16(afrag, bfrag, acc[ct]);
        }
    }
    #pragma unroll
    for (int ct = 0; ct < 12; ct++) {
        int c = 16*ct + lr;
        float bv = bias[c];
        #pragma unroll
        for (int reg = 0; reg < 4; reg++) {
            int r = m0 + 16*wave + 4*lg + reg;
            D[(size_t)r*DIMC + c] = acc[ct][reg] + bv;
        }
    }
}

// ---------------- fused attention: one block (4 waves) per (b,h), 2 q-tiles/wave ----------------
// swapped QK^T: s = mfma(K,Q) -> lane holds q = q0+lr (fixed), m = 32ks+{0,16}+4lg+reg
// P redistribution C-layout -> A-layout done fully in-register via shfl (no P LDS buffer)
#define VT_PITCH 392   // 196 dwords == 4 mod 32: 2-way max on b128 reads
__global__ __launch_bounds__(256, 6) void attn_kernel(
    const __bf16* __restrict__ qb, const __bf16* __restrict__ kb, const __bf16* __restrict__ vb,
    const float* __restrict__ R, const unsigned* __restrict__ mbits,
    __bf16* __restrict__ cross)
{
    __shared__ __bf16 VTs[32*VT_PITCH];   // V^T [d=32][m pitch 392], 25088 B total LDS

    int bh = blockIdx.x;
    int b  = bh / HH;
    int h  = bh - b*HH;
    int w  = b & 63;
    int t  = threadIdx.x;

    const __bf16* Kb = kb + ((size_t)b*NN)*DIMC + 32*h;
    const __bf16* Vb = vb + ((size_t)b*NN)*DIMC + 32*h;
    const __bf16* Qb = qb + ((size_t)b*NN)*DIMC + 32*h;

    // stage V^T (consecutive threads -> consecutive m)
    for (int idx = t; idx < NN*4; idx += 256) {
        int part = idx / NN;
        int m    = idx - part*NN;
        union { uint4 u; __bf16 e[8]; } vv;
        vv.u = *(const uint4*)(Vb + (size_t)m*DIMC + 8*part);
        #pragma unroll
        for (int j = 0; j < 8; j++) {
            int d = 8*part + j;
            VTs[d*VT_PITCH + m] = vv.e[j];
        }
    }
    for (int idx = t; idx < 32*9; idx += 256) {
        int d = idx / 9, m = NN + (idx - d*9);
        VTs[d*VT_PITCH + m] = (__bf16)0.f;
    }
    __syncthreads();

    int wave = t >> 6, lane = t & 63, lr = lane & 15, lg = lane >> 4;
    const f32x4 zero = {0.f,0.f,0.f,0.f};
    // shfl source lanes for the C->A P redistribution
    int srcA = lr + 16*((2*lg)     & 3);
    int srcB = lr + 16*((2*lg + 1) & 3);
    bool hi  = (lg >= 2);

    for (int p = wave; p < 11; p += 4) {
        int q00 = 32*p, q01 = 32*p + 16;
        int rc0 = min(q00 + lr, NN-1);
        int rc1 = min(q01 + lr, NN-1);
        bf16x8 qf0 = *(const bf16x8*)(Qb + (size_t)rc0*DIMC + 8*lg);
        bf16x8 qf1 = *(const bf16x8*)(Qb + (size_t)rc1*DIMC + 8*lg);
        const float* Rrow0 = R + ((size_t)h*NN + rc0)*352 + 4*lg;
        const float* Rrow1 = R + ((size_t)h*NN + rc1)*352 + 4*lg;
        uint4 mu0 = *(const uint4*)(mbits + ((size_t)(w*NN + rc0))*16 + 4*lg);
        uint4 mu1 = *(const uint4*)(mbits + ((size_t)(w*NN + rc1))*16 + 4*lg);
        unsigned t0a = mu0.x, t0b = mu0.y, t0c = mu0.z;
        unsigned t1a = mu1.x, t1b = mu1.y, t1c = mu1.z;

        float dsum0 = 0.f, dsum1 = 0.f;
        f32x4 acc00 = zero, acc01 = zero, acc10 = zero, acc11 = zero;

        // prefetch ks = 0
        bf16x8 kfa = *(const bf16x8*)(Kb + (size_t)lr*DIMC + 8*lg);
        bf16x8 kfb = *(const bf16x8*)(Kb + (size_t)(16+lr)*DIMC + 8*lg);
        f32x4 ra0 = *(const f32x4*)(Rrow0);
        f32x4 rb0 = *(const f32x4*)(Rrow0 + 16);
        f32x4 ra1 = *(const f32x4*)(Rrow1);
        f32x4 rb1 = *(const f32x4*)(Rrow1 + 16);

        for (int ks = 0; ks < 11; ks++) {
            // prefetch ks+1
            bf16x8 kfa_n = kfa, kfb_n = kfb;
            f32x4 ra0_n = ra0, rb0_n = rb0, ra1_n = ra1, rb1_n = rb1;
            if (ks < 10) {
                int ma = 32*(ks+1) + lr;
                kfa_n = *(const bf16x8*)(Kb + (size_t)min(ma, NN-1)*DIMC + 8*lg);
                kfb_n = *(const bf16x8*)(Kb + (size_t)min(ma+16, NN-1)*DIMC + 8*lg);
                ra0_n = *(const f32x4*)(Rrow0 + 32*(ks+1));
                rb0_n = *(const f32x4*)(Rrow0 + 32*(ks+1) + 16);
                ra1_n = *(const f32x4*)(Rrow1 + 32*(ks+1));
                rb1_n = *(const f32x4*)(Rrow1 + 32*(ks+1) + 16);
            }

            f32x4 s0a = mfma16(kfa, qf0, zero);
            f32x4 s0b = mfma16(kfb, qf0, zero);
            f32x4 s1a = mfma16(kfa, qf1, zero);
            f32x4 s1b = mfma16(kfb, qf1, zero);

            unsigned nib0 = t0a & 0xFFu;
            t0a = (t0a >> 8) | (t0b << 24); t0b = (t0b >> 8) | (t0c << 24); t0c >>= 8;
            unsigned nib1 = t1a & 0xFFu;
            t1a = (t1a >> 8) | (t1b << 24); t1b = (t1b >> 8) | (t1c << 24); t1c >>= 8;

            bf16x8 paf0, paf1;
            // tile 0: numerators + in-register C->A redistribution
            {
                float pa[4], pb[4];
                #pragma unroll
                for (int r = 0; r < 4; r++) {
                    pa[r] = ((nib0 >> r) & 1)     ? __builtin_amdgcn_exp2f(s0a[r]) * ra0[r] : 0.f;
                    pb[r] = ((nib0 >> (4+r)) & 1) ? __builtin_amdgcn_exp2f(s0b[r]) * rb0[r] : 0.f;
                    dsum0 += pa[r] + pb[r];
                }
                unsigned ua0 = pack2(pa[0], pa[1]), ua1 = pack2(pa[2], pa[3]);
                unsigned ub0 = pack2(pb[0], pb[1]), ub1 = pack2(pb[2], pb[3]);
                unsigned x0 = __shfl(ua0, srcA), x1 = __shfl(ua1, srcA);
                unsigned x2 = __shfl(ua0, srcB), x3 = __shfl(ua1, srcB);
                unsigned y0 = __shfl(ub0, srcA), y1 = __shfl(ub1, srcA);
                unsigned y2 = __shfl(ub0, srcB), y3 = __shfl(ub1, srcB);
                union { unsigned u[4]; bf16x8 f; } fr;
                fr.u[0] = hi ? y0 : x0; fr.u[1] = hi ? y1 : x1;
                fr.u[2] = hi ? y2 : x2; fr.u[3] = hi ? y3 : x3;
                paf0 = fr.f;
            }
            // tile 1
            {
                float pa[4], pb[4];
                #pragma unroll
                for (int r = 0; r < 4; r++) {
                    pa[r] = ((nib1 >> r) & 1)     ? __builtin_amdgcn_exp2f(s1a[r]) * ra1[r] : 0.f;
                    pb[r] = ((nib1 >> (4+r)) & 1) ? __builtin_amdgcn_exp2f(s1b[r]) * rb1[r] : 0.f;
                    dsum1 += pa[r] + pb[r];
                }
                unsigned ua0 = pack2(pa[0], pa[1]), ua1 = pack2(pa[2], pa[3]);
                unsigned ub0 = pack2(pb[0], pb[1]), ub1 = pack2(pb[2], pb[3]);
                unsigned x0 = __shfl(ua0, srcA), x1 = __shfl(ua1, srcA);
                unsigned x2 = __shfl(ua0, srcB), x3 = __shfl(ua1, srcB);
                unsigned y0 = __shfl(ub0, srcA), y1 = __shfl(ub1, srcA);
                unsigned y2 = __shfl(ub0, srcB), y3 = __shfl(ub1, srcB);
                union { unsigned u[4]; bf16x8 f; } fr;
                fr.u[0] = hi ? y0 : x0; fr.u[1] = hi ? y1 : x1;
                fr.u[2] = hi ? y2 : x2; fr.u[3] = hi ? y3 : x3;
                paf1 = fr.f;
            }

            bf16x8 v0 = *(const bf16x8*)&VTs[lr*VT_PITCH      + 32*ks + 8*lg];
            bf16x8 v1 = *(const bf16x8*)&VTs[(16+lr)*VT_PITCH + 32*ks + 8*lg];
            acc00 = mfma16(paf0, v0, acc00);
            acc01 = mfma16(paf0, v1, acc01);
            acc10 = mfma16(paf1, v0, acc10);
            acc11 = mfma16(paf1, v1, acc11);

            kfa = kfa_n; kfb = kfb_n;
            ra0 = ra0_n; rb0 = rb0_n; ra1 = ra1_n; rb1 = rb1_n;
        }

        dsum0 += __shfl_xor(dsum0, 16); dsum0 += __shfl_xor(dsum0, 32);
        dsum1 += __shfl_xor(dsum1, 16); dsum1 += __shfl_xor(dsum1, 32);
        float dinv0 = 1.f / dsum0;
        float dinv1 = 1.f / dsum1;

        #pragma unroll
        for (int reg = 0; reg < 4; reg++) {
            float dv0 = __shfl(dinv0, 4*lg + reg);
            float dv1 = __shfl(dinv1, 4*lg + reg);
            int q0v = q00 + 4*lg + reg;
            int q1v = q01 + 4*lg + reg;
            if (q0v < NN) {
                size_t cb = ((size_t)b*NN + q0v)*DIMC + 32*h;
                cross[cb + lr]      = (__bf16)(acc00[reg] * dv0);
                cross[cb + 16 + lr] = (__bf16)(acc01[reg] * dv0);
            }
            if (q1v < NN) {
                size_t cb = ((size_t)b*NN + q1v)*DIMC + 32*h;
                cross[cb + lr]      = (__bf16)(acc10[reg] * dv1);
                cross[cb + 16 + lr] = (__bf16)(acc11[reg] * dv1);
            }
        }
    }
}

extern "C" void kernel_launch(void* const* d_in, const int* in_sizes, int n_in,
                              void* d_out, int out_size, void* d_ws, size_t ws_size,
                              hipStream_t stream) {
    const float* x           = (const float*)d_in[0];
    const float* y           = (const float*)d_in[1];
    const float* mask        = (const float*)d_in[2];
    const float* qkv1_w      = (const float*)d_in[3];
    const float* qkv2_w      = (const float*)d_in[4];
    const float* v1_bias     = (const float*)d_in[6];
    const float* q2_bias     = (const float*)d_in[7];
    const float* logit_scale = (const float*)d_in[9];
    const float* cpb_w1      = (const float*)d_in[10];
    const float* cpb_b1      = (const float*)d_in[11];
    const float* cpb_w2      = (const float*)d_in[12];
    const float* proj_w      = (const float*)d_in[13];
    const float* proj_b      = (const float*)d_in[14];
    const float* rel_table   = (const float*)d_in[15];
    const int*   rp_index    = (const int*)d_in[16];

    char* ws = (char*)d_ws;
    float*    table  = (float*)(ws + OFF_TABLE);
    float*    R      = (float*)(ws + OFF_R);
    unsigned* mb     = (unsigned*)(ws + OFF_MB);
    __bf16*   q_bf   = (__bf16*)(ws + OFF_QB);
    __bf16*   k_bf   = (__bf16*)(ws + OFF_KB);
    __bf16*   v_bf   = (__bf16*)(ws + OFF_VB);
    __bf16*   crossb = (__bf16*)(ws + OFF_CROSS);

    cpb_table_kernel<<<2197, 256, 0, stream>>>(rel_table, cpb_w1, cpb_b1, cpb_w2, table);
    r_kernel<<<(HH*NN*352 + 255)/256, 256, 0, stream>>>(table, rp_index, R);
    mbits_kernel<<<(64*NN*4)/256, 256, 0, stream>>>(mask, mb);
    // x -> k (norm, no bias), v (+v1_bias, no norm)
    gemm_f32in<<<MM/64, 256, 0, stream>>>(x, logit_scale,
                                          qkv1_w + 192*192, nullptr, 1, k_bf,
                                          qkv1_w + 384*192, v1_bias, 0, v_bf);
    // y -> q (+q2_bias, norm+scale*log2e)
    gemm_f32in<<<MM/64, 256, 0, stream>>>(y, logit_scale,
                                          qkv2_w, q2_bias, 2, q_bf,
                                          nullptr, nullptr, 0, nullptr);

    attn_kernel<<<BB*HH, 256, 0, stream>>>(q_bf, k_bf, v_bf, R, mb, crossb);

    gemm_proj<<<MM/64, 256, 0, stream>>>(crossb, proj_w, proj_b, (float*)d_out);
}

// Round 7
// 645.944 us; speedup vs baseline: 1.2809x; 1.2809x over previous
//
#include <hip/hip_runtime.h>

#define HH   6
#define NN   343
#define BB   512
#define DIMC 192
#define MM   (BB*NN)      // 175616

// workspace offsets (bytes)
#define OFF_TABLE 0                        // [2197][8] f32
#define OFF_R     70400                    // [6][343][352] f32  (exp(rpb-26), zero tail)
#define OFF_MB    2968064                  // [64*343][16] u32   (bit-packed mask, lane-repacked)
#define OFF_QB    4372992                  // [M][192] bf16 (normalized * scale * log2e)
#define OFF_KB    (OFF_QB + 67436544)      // [M][192] bf16 (normalized)
#define OFF_VB    (OFF_KB + 67436544)
#define OFF_CROSS (OFF_VB + 67436544)
// end = 274,119,168 bytes

typedef __bf16 bf16x8 __attribute__((ext_vector_type(8)));
typedef float  f32x4  __attribute__((ext_vector_type(4)));

__device__ __forceinline__ f32x4 mfma16(bf16x8 a, bf16x8 b, f32x4 c) {
    return __builtin_amdgcn_mfma_f32_16x16x32_bf16(a, b, c, 0, 0, 0);
}

__device__ __forceinline__ unsigned pack2(float a, float b) {
    union { __bf16 h[2]; unsigned u; } x;
    x.h[0] = (__bf16)a; x.h[1] = (__bf16)b;
    return x.u;
}

// ---------------- K1: CPB MLP -> table[2197][8] ----------------
__global__ __launch_bounds__(256) void cpb_table_kernel(
    const float* __restrict__ rel_table, const float* __restrict__ w1,
    const float* __restrict__ b1, const float* __restrict__ w2,
    float* __restrict__ table)
{
    int i = blockIdx.x;
    int t = threadIdx.x;
    float t0 = rel_table[i*3+0], t1 = rel_table[i*3+1], t2 = rel_table[i*3+2];
    float acc[HH];
    #pragma unroll
    for (int h = 0; h < HH; h++) acc[h] = 0.f;
    for (int j = t; j < 512; j += 256) {
        float hv = w1[j*3+0]*t0 + w1[j*3+1]*t1 + w1[j*3+2]*t2 + b1[j];
        hv = fmaxf(hv, 0.f);
        #pragma unroll
        for (int h = 0; h < HH; h++) acc[h] += w2[h*512+j] * hv;
    }
    __shared__ float red[256*HH];
    #pragma unroll
    for (int h = 0; h < HH; h++) red[t*HH+h] = acc[h];
    __syncthreads();
    for (int s = 128; s > 0; s >>= 1) {
        if (t < s) {
            #pragma unroll
            for (int h = 0; h < HH; h++) red[t*HH+h] += red[(t+s)*HH+h];
        }
        __syncthreads();
    }
    if (t < HH) table[(size_t)i*8 + t] = red[t];
}

// ---------------- K2: R = exp(16*sigmoid(gather) - 26), [6][343][352] ----------------
__global__ __launch_bounds__(256) void r_kernel(
    const float* __restrict__ table, const int* __restrict__ rp_index,
    float* __restrict__ R)
{
    int id = blockIdx.x*256 + threadIdx.x;
    if (id >= HH*NN*352) return;
    int h   = id / (NN*352);
    int rem = id - h*(NN*352);
    int n   = rem / 352;
    int mc  = rem - n*352;
    float out = 0.f;
    if (mc < NN) {
        float v = table[(size_t)rp_index[n*NN+mc]*8 + h];
        float r = 16.f / (1.f + __expf(-v));
        out = __expf(r - 26.f);
    }
    R[id] = out;
}

// ---------------- K3: bit-pack mask, lane-stream layout ----------------
__global__ __launch_bounds__(256) void mbits_kernel(
    const float* __restrict__ mask, unsigned* __restrict__ mb)
{
    int id  = blockIdx.x*256 + threadIdx.x;   // 64*343*4 threads
    int lg  = id & 3;
    int row = id >> 2;                         // w*343 + n
    const float* mrow = mask + (size_t)row*NN;
    unsigned out[3];
    #pragma unroll
    for (int t = 0; t < 3; t++) {
        unsigned u = 0;
        #pragma unroll
        for (int bb = 0; bb < 32; bb++) {
            int mt = 8*t + (bb>>2), r = bb & 3;
            int m  = 16*mt + 4*lg + r;
            if (m < NN && mrow[m] > -50.f) u |= (1u << bb);
        }
        out[t] = u;
    }
    *(uint4*)(mb + (size_t)row*16 + 4*lg) = make_uint4(out[0], out[1], out[2], 0u);
}

// ---------------- GEMM: f32 in -> bf16 out, tile 64x192, K=192, up to 2 phases (LDS-staged) ----------------
// norm: 0 = none, 1 = k-norm (1/|k|), 2 = q-norm (scale*log2e/|q|)
__global__ __launch_bounds__(256) void gemm_f32in(
    const float* __restrict__ A, const float* __restrict__ ls,
    const float* __restrict__ W0, const float* __restrict__ bias0, int norm0, __bf16* __restrict__ D0,
    const float* __restrict__ W1, const float* __restrict__ bias1, int norm1, __bf16* __restrict__ D1)
{
    __shared__ __bf16 As[64][200];
    __shared__ __bf16 Ws[192][40];
    int m0 = blockIdx.x * 64;
    int t  = threadIdx.x;
    #pragma unroll
    for (int i = 0; i < 12; i++) {
        int f = t + 256*i;
        int row = f / 48, ch = (f - row*48) * 4;
        float4 v = *(const float4*)(A + (size_t)(m0+row)*DIMC + ch);
        __bf16* dst = &As[row][ch];
        dst[0] = (__bf16)v.x; dst[1] = (__bf16)v.y; dst[2] = (__bf16)v.z; dst[3] = (__bf16)v.w;
    }
    int wave = t >> 6, lane = t & 63, lr = lane & 15, lg = lane >> 4;
    for (int phase = 0; phase < 2; phase++) {
        const float* W    = phase ? W1 : W0;
        if (!W) break;
        const float* bias = phase ? bias1 : bias0;
        int          nrm  = phase ? norm1 : norm0;
        __bf16*      D    = phase ? D1 : D0;
        f32x4 acc[12];
        #pragma unroll
        for (int i = 0; i < 12; i++) acc[i] = (f32x4){0.f,0.f,0.f,0.f};
        for (int ks = 0; ks < 6; ks++) {
            __syncthreads();
            #pragma unroll
            for (int i = 0; i < 6; i++) {
                int f = t + 256*i;
                int row = f / 8, ch = (f - row*8) * 4;
                float4 v = *(const float4*)(W + (size_t)row*DIMC + ks*32 + ch);
                __bf16* dst = &Ws[row][ch];
                dst[0] = (__bf16)v.x; dst[1] = (__bf16)v.y; dst[2] = (__bf16)v.z; dst[3] = (__bf16)v.w;
            }
            __syncthreads();
            bf16x8 afrag = *(const bf16x8*)&As[16*wave + lr][ks*32 + 8*lg];
            #pragma unroll
            for (int ct = 0; ct < 12; ct++) {
                bf16x8 bfrag = *(const bf16x8*)&Ws[16*ct + lr][8*lg];
                acc[ct] = mfma16(afrag, bfrag, acc[ct]);
            }
        }
        if (bias) {
            #pragma unroll
            for (int ct = 0; ct < 12; ct++) {
                float bv = bias[16*ct + lr];
                #pragma unroll
                for (int reg = 0; reg < 4; reg++) acc[ct][reg] += bv;
            }
        }
        if (nrm) {
            #pragma unroll
            for (int h = 0; h < HH; h++) {
                float sc = 1.f;
                if (nrm == 2) sc = __expf(fminf(ls[h], 4.6051702f)) * 1.4426950408889634f;
                #pragma unroll
                for (int reg = 0; reg < 4; reg++) {
                    float ss = acc[2*h][reg]*acc[2*h][reg] + acc[2*h+1][reg]*acc[2*h+1][reg];
                    ss += __shfl_xor(ss, 1); ss += __shfl_xor(ss, 2);
                    ss += __shfl_xor(ss, 4); ss += __shfl_xor(ss, 8);
                    float f = sc / fmaxf(sqrtf(ss), 1e-12f);
                    acc[2*h][reg]   *= f;
                    acc[2*h+1][reg] *= f;
                }
            }
        }
        #pragma unroll
        for (int ct = 0; ct < 12; ct++) {
            int c = 16*ct + lr;
            #pragma unroll
            for (int reg = 0; reg < 4; reg++) {
                int r = m0 + 16*wave + 4*lg + reg;
                D[(size_t)r*DIMC + c] = (__bf16)acc[ct][reg];
            }
        }
    }
}

// ---------------- proj GEMM: bf16 in -> f32 out + bias (LDS-staged) ----------------
__global__ __launch_bounds__(256) void gemm_proj(
    const __bf16* __restrict__ A, const float* __restrict__ W,
    const float* __restrict__ bias, float* __restrict__ D)
{
    __shared__ __bf16 As[64][200];
    __shared__ __bf16 Ws[192][40];
    int m0 = blockIdx.x * 64;
    int t  = threadIdx.x;
    #pragma unroll
    for (int i = 0; i < 6; i++) {
        int f = t + 256*i;
        int row = f / 24, ch = (f - row*24) * 8;
        uint4 v = *(const uint4*)(A + (size_t)(m0+row)*DIMC + ch);
        *(uint4*)&As[row][ch] = v;
    }
    int wave = t >> 6, lane = t & 63, lr = lane & 15, lg = lane >> 4;
    f32x4 acc[12];
    #pragma unroll
    for (int i = 0; i < 12; i++) acc[i] = (f32x4){0.f,0.f,0.f,0.f};
    for (int ks = 0; ks < 6; ks++) {
        __syncthreads();
        #pragma unroll
        for (int i = 0; i < 6; i++) {
            int f = t + 256*i;
            int row = f / 8, ch = (f - row*8) * 4;
            float4 v = *(const float4*)(W + (size_t)row*DIMC + ks*32 + ch);
            __bf16* dst = &Ws[row][ch];
            dst[0] = (__bf16)v.x; dst[1] = (__bf16)v.y; dst[2] = (__bf16)v.z; dst[3] = (__bf16)v.w;
        }
        __syncthreads();
        bf16x8 afrag = *(const bf16x8*)&As[16*wave + lr][ks*32 + 8*lg];
        #pragma unroll
        for (int ct = 0; ct < 12; ct++) {
            bf16x8 bfrag = *(const bf16x8*)&Ws[16*ct + lr][8*lg];
            acc[ct] = mfma16(afrag, bfrag, acc[ct]);
        }
    }
    #pragma unroll
    for (int ct = 0; ct < 12; ct++) {
        int c = 16*ct + lr;
        float bv = bias[c];
        #pragma unroll
        for (int reg = 0; reg < 4; reg++) {
            int r = m0 + 16*wave + 4*lg + reg;
            D[(size_t)r*DIMC + c] = acc[ct][reg] + bv;
        }
    }
}

// ---------------- fused attention: one block (4 waves) per (b,h), 2 q-tiles/wave ----------------
// swapped QK^T: s = mfma(K,Q) -> lane holds q = q0+lr (fixed), m = 32ks+{0,16}+4lg+reg
// P redistribution C-layout -> A-layout fully in-register via shfl (no P LDS buffer)
#define VT_PITCH 360   // 180 dwords == 20 mod 32: 2-way max on b128 reads (free)
__global__ __launch_bounds__(256, 4) void attn_kernel(
    const __bf16* __restrict__ qb, const __bf16* __restrict__ kb, const __bf16* __restrict__ vb,
    const float* __restrict__ R, const unsigned* __restrict__ mbits,
    __bf16* __restrict__ cross)
{
    __shared__ __bf16 VTs[32*VT_PITCH];   // V^T [d=32][m pitch 360], 23040 B total LDS

    int bh = blockIdx.x;
    int b  = bh / HH;
    int h  = bh - b*HH;
    int w  = b & 63;
    int t  = threadIdx.x;

    const __bf16* Kb = kb + ((size_t)b*NN)*DIMC + 32*h;
    const __bf16* Vb = vb + ((size_t)b*NN)*DIMC + 32*h;
    const __bf16* Qb = qb + ((size_t)b*NN)*DIMC + 32*h;

    // stage V^T (consecutive threads -> consecutive m)
    for (int idx = t; idx < NN*4; idx += 256) {
        int part = idx / NN;
        int m    = idx - part*NN;
        union { uint4 u; __bf16 e[8]; } vv;
        vv.u = *(const uint4*)(Vb + (size_t)m*DIMC + 8*part);
        #pragma unroll
        for (int j = 0; j < 8; j++) {
            int d = 8*part + j;
            VTs[d*VT_PITCH + m] = vv.e[j];
        }
    }
    for (int idx = t; idx < 32*9; idx += 256) {
        int d = idx / 9, m = NN + (idx - d*9);
        VTs[d*VT_PITCH + m] = (__bf16)0.f;
    }
    __syncthreads();

    int wave = t >> 6, lane = t & 63, lr = lane & 15, lg = lane >> 4;
    const f32x4 zero = {0.f,0.f,0.f,0.f};
    // shfl source lanes for the C->A P redistribution
    int srcA = lr + 16*((2*lg)     & 3);
    int srcB = lr + 16*((2*lg + 1) & 3);
    bool hi  = (lg >= 2);

    for (int p = wave; p < 11; p += 4) {
        int q00 = 32*p, q01 = 32*p + 16;
        int rc0 = min(q00 + lr, NN-1);
        int rc1 = min(q01 + lr, NN-1);
        bf16x8 qf0 = *(const bf16x8*)(Qb + (size_t)rc0*DIMC + 8*lg);
        bf16x8 qf1 = *(const bf16x8*)(Qb + (size_t)rc1*DIMC + 8*lg);
        const float* Rrow0 = R + ((size_t)h*NN + rc0)*352 + 4*lg;
        const float* Rrow1 = R + ((size_t)h*NN + rc1)*352 + 4*lg;
        uint4 mu0 = *(const uint4*)(mbits + ((size_t)(w*NN + rc0))*16 + 4*lg);
        uint4 mu1 = *(const uint4*)(mbits + ((size_t)(w*NN + rc1))*16 + 4*lg);
        unsigned t0a = mu0.x, t0b = mu0.y, t0c = mu0.z;
        unsigned t1a = mu1.x, t1b = mu1.y, t1c = mu1.z;

        float dsum0 = 0.f, dsum1 = 0.f;
        f32x4 acc00 = zero, acc01 = zero, acc10 = zero, acc11 = zero;

        // prefetch K for ks = 0
        bf16x8 kfa = *(const bf16x8*)(Kb + (size_t)lr*DIMC + 8*lg);
        bf16x8 kfb = *(const bf16x8*)(Kb + (size_t)(16+lr)*DIMC + 8*lg);

        for (int ks = 0; ks < 11; ks++) {
            // issue this-iter R loads (consumed after the 4 QK MFMAs)
            f32x4 ra0 = *(const f32x4*)(Rrow0 + 32*ks);
            f32x4 rb0 = *(const f32x4*)(Rrow0 + 32*ks + 16);
            f32x4 ra1 = *(const f32x4*)(Rrow1 + 32*ks);
            f32x4 rb1 = *(const f32x4*)(Rrow1 + 32*ks + 16);
            // prefetch K for ks+1
            bf16x8 kfa_n = kfa, kfb_n = kfb;
            if (ks < 10) {
                int ma = 32*(ks+1) + lr;
                kfa_n = *(const bf16x8*)(Kb + (size_t)min(ma, NN-1)*DIMC + 8*lg);
                kfb_n = *(const bf16x8*)(Kb + (size_t)min(ma+16, NN-1)*DIMC + 8*lg);
            }

            f32x4 s0a = mfma16(kfa, qf0, zero);
            f32x4 s0b = mfma16(kfb, qf0, zero);
            f32x4 s1a = mfma16(kfa, qf1, zero);
            f32x4 s1b = mfma16(kfb, qf1, zero);

            unsigned nib0 = t0a & 0xFFu;
            t0a = (t0a >> 8) | (t0b << 24); t0b = (t0b >> 8) | (t0c << 24); t0c >>= 8;
            unsigned nib1 = t1a & 0xFFu;
            t1a = (t1a >> 8) | (t1b << 24); t1b = (t1b >> 8) | (t1c << 24); t1c >>= 8;

            bf16x8 paf0, paf1;
            // tile 0: numerators + in-register C->A redistribution
            {
                float pa[4], pb[4];
                #pragma unroll
                for (int r = 0; r < 4; r++) {
                    pa[r] = ((nib0 >> r) & 1)     ? __builtin_amdgcn_exp2f(s0a[r]) * ra0[r] : 0.f;
                    pb[r] = ((nib0 >> (4+r)) & 1) ? __builtin_amdgcn_exp2f(s0b[r]) * rb0[r] : 0.f;
                    dsum0 += pa[r] + pb[r];
                }
                unsigned ua0 = pack2(pa[0], pa[1]), ua1 = pack2(pa[2], pa[3]);
                unsigned ub0 = pack2(pb[0], pb[1]), ub1 = pack2(pb[2], pb[3]);
                unsigned x0 = __shfl(ua0, srcA), x1 = __shfl(ua1, srcA);
                unsigned x2 = __shfl(ua0, srcB), x3 = __shfl(ua1, srcB);
                unsigned y0 = __shfl(ub0, srcA), y1 = __shfl(ub1, srcA);
                unsigned y2 = __shfl(ub0, srcB), y3 = __shfl(ub1, srcB);
                union { unsigned u[4]; bf16x8 f; } fr;
                fr.u[0] = hi ? y0 : x0; fr.u[1] = hi ? y1 : x1;
                fr.u[2] = hi ? y2 : x2; fr.u[3] = hi ? y3 : x3;
                paf0 = fr.f;
            }
            // tile 1
            {
                float pa[4], pb[4];
                #pragma unroll
                for (int r = 0; r < 4; r++) {
                    pa[r] = ((nib1 >> r) & 1)     ? __builtin_amdgcn_exp2f(s1a[r]) * ra1[r] : 0.f;
                    pb[r] = ((nib1 >> (4+r)) & 1) ? __builtin_amdgcn_exp2f(s1b[r]) * rb1[r] : 0.f;
                    dsum1 += pa[r] + pb[r];
                }
                unsigned ua0 = pack2(pa[0], pa[1]), ua1 = pack2(pa[2], pa[3]);
                unsigned ub0 = pack2(pb[0], pb[1]), ub1 = pack2(pb[2], pb[3]);
                unsigned x0 = __shfl(ua0, srcA), x1 = __shfl(ua1, srcA);
                unsigned x2 = __shfl(ua0, srcB), x3 = __shfl(ua1, srcB);
                unsigned y0 = __shfl(ub0, srcA), y1 = __shfl(ub1, srcA);
                unsigned y2 = __shfl(ub0, srcB), y3 = __shfl(ub1, srcB);
                union { unsigned u[4]; bf16x8 f; } fr;
                fr.u[0] = hi ? y0 : x0; fr.u[1] = hi ? y1 : x1;
                fr.u[2] = hi ? y2 : x2; fr.u[3] = hi ? y3 : x3;
                paf1 = fr.f;
            }

            bf16x8 v0 = *(const bf16x8*)&VTs[lr*VT_PITCH      + 32*ks + 8*lg];
            bf16x8 v1 = *(const bf16x8*)&VTs[(16+lr)*VT_PITCH + 32*ks + 8*lg];
            acc00 = mfma16(paf0, v0, acc00);
            acc01 = mfma16(paf0, v1, acc01);
            acc10 = mfma16(paf1, v0, acc10);
            acc11 = mfma16(paf1, v1, acc11);

            kfa = kfa_n; kfb = kfb_n;
        }

        dsum0 += __shfl_xor(dsum0, 16); dsum0 += __shfl_xor(dsum0, 32);
        dsum1 += __shfl_xor(dsum1, 16); dsum1 += __shfl_xor(dsum1, 32);
        float dinv0 = 1.f / dsum0;
        float dinv1 = 1.f / dsum1;

        #pragma unroll
        for (int reg = 0; reg < 4; reg++) {
            float dv0 = __shfl(dinv0, 4*lg + reg);
            float dv1 = __shfl(dinv1, 4*lg + reg);
            int q0v = q00 + 4*lg + reg;
            int q1v = q01 + 4*lg + reg;
            if (q0v < NN) {
                size_t cb = ((size_t)b*NN + q0v)*DIMC + 32*h;
                cross[cb + lr]      = (__bf16)(acc00[reg] * dv0);
                cross[cb + 16 + lr] = (__bf16)(acc01[reg] * dv0);
            }
            if (q1v < NN) {
                size_t cb = ((size_t)b*NN + q1v)*DIMC + 32*h;
                cross[cb + lr]      = (__bf16)(acc10[reg] * dv1);
                cross[cb + 16 + lr] = (__bf16)(acc11[reg] * dv1);
            }
        }
    }
}

extern "C" void kernel_launch(void* const* d_in, const int* in_sizes, int n_in,
                              void* d_out, int out_size, void* d_ws, size_t ws_size,
                              hipStream_t stream) {
    const float* x           = (const float*)d_in[0];
    const float* y           = (const float*)d_in[1];
    const float* mask        = (const float*)d_in[2];
    const float* qkv1_w      = (const float*)d_in[3];
    const float* qkv2_w      = (const float*)d_in[4];
    const float* v1_bias     = (const float*)d_in[6];
    const float* q2_bias     = (const float*)d_in[7];
    const float* logit_scale = (const float*)d_in[9];
    const float* cpb_w1      = (const float*)d_in[10];
    const float* cpb_b1      = (const float*)d_in[11];
    const float* cpb_w2      = (const float*)d_in[12];
    const float* proj_w      = (const float*)d_in[13];
    const float* proj_b      = (const float*)d_in[14];
    const float* rel_table   = (const float*)d_in[15];
    const int*   rp_index    = (const int*)d_in[16];

    char* ws = (char*)d_ws;
    float*    table  = (float*)(ws + OFF_TABLE);
    float*    R      = (float*)(ws + OFF_R);
    unsigned* mb     = (unsigned*)(ws + OFF_MB);
    __bf16*   q_bf   = (__bf16*)(ws + OFF_QB);
    __bf16*   k_bf   = (__bf16*)(ws + OFF_KB);
    __bf16*   v_bf   = (__bf16*)(ws + OFF_VB);
    __bf16*   crossb = (__bf16*)(ws + OFF_CROSS);

    cpb_table_kernel<<<2197, 256, 0, stream>>>(rel_table, cpb_w1, cpb_b1, cpb_w2, table);
    r_kernel<<<(HH*NN*352 + 255)/256, 256, 0, stream>>>(table, rp_index, R);
    mbits_kernel<<<(64*NN*4)/256, 256, 0, stream>>>(mask, mb);
    // x -> k (norm, no bias), v (+v1_bias, no norm)
    gemm_f32in<<<MM/64, 256, 0, stream>>>(x, logit_scale,
                                          qkv1_w + 192*192, nullptr, 1, k_bf,
                                          qkv1_w + 384*192, v1_bias, 0, v_bf);
    // y -> q (+q2_bias, norm+scale*log2e)
    gemm_f32in<<<MM/64, 256, 0, stream>>>(y, logit_scale,
                                          qkv2_w, q2_bias, 2, q_bf,
                                          nullptr, nullptr, 0, nullptr);

    attn_kernel<<<BB*HH, 256, 0, stream>>>(q_bf, k_bf, v_bf, R, mb, crossb);

    gemm_proj<<<MM/64, 256, 0, stream>>>(crossb, proj_w, proj_b, (float*)d_out);
}

// Round 8
// 632.297 us; speedup vs baseline: 1.3086x; 1.0216x over previous
//
#include <hip/hip_runtime.h>

#define HH   6
#define NN   343
#define BB   512
#define DIMC 192
#define MM   (BB*NN)      // 175616

// workspace offsets (bytes)
#define OFF_TABLE 0                        // [2197][8] f32
#define OFF_R     70400                    // [6][343][352] f32  (exp(rpb-26), zero tail)
#define OFF_MB    2968064                  // [64*343][16] u32   (bit-packed mask, 32x32-reg order)
#define OFF_QB    4372992                  // [M][192] bf16 (normalized * scale * log2e)
#define OFF_KB    (OFF_QB + 67436544)      // [M][192] bf16 (normalized)
#define OFF_VB    (OFF_KB + 67436544)
#define OFF_CROSS (OFF_VB + 67436544)
// end = 274,119,168 bytes

typedef __bf16 bf16x8 __attribute__((ext_vector_type(8)));
typedef float  f32x4  __attribute__((ext_vector_type(4)));
typedef float  f32x16 __attribute__((ext_vector_type(16)));

__device__ __forceinline__ f32x4 mfma16(bf16x8 a, bf16x8 b, f32x4 c) {
    return __builtin_amdgcn_mfma_f32_16x16x32_bf16(a, b, c, 0, 0, 0);
}
__device__ __forceinline__ f32x16 mfma32(bf16x8 a, bf16x8 b, f32x16 c) {
    return __builtin_amdgcn_mfma_f32_32x32x16_bf16(a, b, c, 0, 0, 0);
}

__device__ __forceinline__ unsigned pack2(float a, float b) {
    union { __bf16 h[2]; unsigned u; } x;
    x.h[0] = (__bf16)a; x.h[1] = (__bf16)b;
    return x.u;
}
// swaps a[32:63] <-> b[0:31]
__device__ __forceinline__ void pl32_swap(unsigned &a, unsigned &b) {
    asm volatile("v_permlane32_swap_b32 %0, %1" : "+v"(a), "+v"(b));
}

// ---------------- K1: CPB MLP -> table[2197][8] ----------------
__global__ __launch_bounds__(256) void cpb_table_kernel(
    const float* __restrict__ rel_table, const float* __restrict__ w1,
    const float* __restrict__ b1, const float* __restrict__ w2,
    float* __restrict__ table)
{
    int i = blockIdx.x;
    int t = threadIdx.x;
    float t0 = rel_table[i*3+0], t1 = rel_table[i*3+1], t2 = rel_table[i*3+2];
    float acc[HH];
    #pragma unroll
    for (int h = 0; h < HH; h++) acc[h] = 0.f;
    for (int j = t; j < 512; j += 256) {
        float hv = w1[j*3+0]*t0 + w1[j*3+1]*t1 + w1[j*3+2]*t2 + b1[j];
        hv = fmaxf(hv, 0.f);
        #pragma unroll
        for (int h = 0; h < HH; h++) acc[h] += w2[h*512+j] * hv;
    }
    __shared__ float red[256*HH];
    #pragma unroll
    for (int h = 0; h < HH; h++) red[t*HH+h] = acc[h];
    __syncthreads();
    for (int s = 128; s > 0; s >>= 1) {
        if (t < s) {
            #pragma unroll
            for (int h = 0; h < HH; h++) red[t*HH+h] += red[(t+s)*HH+h];
        }
        __syncthreads();
    }
    if (t < HH) table[(size_t)i*8 + t] = red[t];
}

// ---------------- K2: R = exp(16*sigmoid(gather) - 26), [6][343][352] ----------------
__global__ __launch_bounds__(256) void r_kernel(
    const float* __restrict__ table, const int* __restrict__ rp_index,
    float* __restrict__ R)
{
    int id = blockIdx.x*256 + threadIdx.x;
    if (id >= HH*NN*352) return;
    int h   = id / (NN*352);
    int rem = id - h*(NN*352);
    int n   = rem / 352;
    int mc  = rem - n*352;
    float out = 0.f;
    if (mc < NN) {
        float v = table[(size_t)rp_index[n*NN+mc]*8 + h];
        float r = 16.f / (1.f + __expf(-v));
        out = __expf(r - 26.f);
    }
    R[id] = out;
}

// ---------------- K3: bit-pack mask for 32x32 reg order ----------------
// mb2[w*343+n][hi*8 + wd]; bit p of word wd: g=32wd+p, ks=g>>4, r=g&15,
// m = 32ks + (r&3) + 8*(r>>2) + 4*hi ; bit = (m<343 && mask>-50)
__global__ __launch_bounds__(256) void mbits2_kernel(
    const float* __restrict__ mask, unsigned* __restrict__ mb)
{
    int id = blockIdx.x*256 + threadIdx.x;    // 64*343*2 threads
    if (id >= 64*NN*2) return;
    int hi  = id & 1;
    int row = id >> 1;                         // w*343 + n
    const float* mrow = mask + (size_t)row*NN;
    unsigned* out = mb + (size_t)row*16 + hi*8;
    #pragma unroll
    for (int wd = 0; wd < 6; wd++) {
        unsigned u = 0;
        #pragma unroll
        for (int p = 0; p < 32; p++) {
            int g = 32*wd + p;
            int ks = g >> 4, r = g & 15;
            int m = 32*ks + (r&3) + 8*(r>>2) + 4*hi;
            if (m < NN && mrow[m] > -50.f) u |= (1u << p);
        }
        out[wd] = u;
    }
    out[6] = 0u; out[7] = 0u;
}

// ---------------- GEMM: f32 in -> bf16 out, tile 64x192, K=192, up to 2 phases (LDS-staged) ----------------
// norm: 0 = none, 1 = k-norm (1/|k|), 2 = q-norm (scale*log2e/|q|)
__global__ __launch_bounds__(256) void gemm_f32in(
    const float* __restrict__ A, const float* __restrict__ ls,
    const float* __restrict__ W0, const float* __restrict__ bias0, int norm0, __bf16* __restrict__ D0,
    const float* __restrict__ W1, const float* __restrict__ bias1, int norm1, __bf16* __restrict__ D1)
{
    __shared__ __bf16 As[64][200];
    __shared__ __bf16 Ws[192][40];
    int m0 = blockIdx.x * 64;
    int t  = threadIdx.x;
    #pragma unroll
    for (int i = 0; i < 12; i++) {
        int f = t + 256*i;
        int row = f / 48, ch = (f - row*48) * 4;
        float4 v = *(const float4*)(A + (size_t)(m0+row)*DIMC + ch);
        __bf16* dst = &As[row][ch];
        dst[0] = (__bf16)v.x; dst[1] = (__bf16)v.y; dst[2] = (__bf16)v.z; dst[3] = (__bf16)v.w;
    }
    int wave = t >> 6, lane = t & 63, lr = lane & 15, lg = lane >> 4;
    for (int phase = 0; phase < 2; phase++) {
        const float* W    = phase ? W1 : W0;
        if (!W) break;
        const float* bias = phase ? bias1 : bias0;
        int          nrm  = phase ? norm1 : norm0;
        __bf16*      D    = phase ? D1 : D0;
        f32x4 acc[12];
        #pragma unroll
        for (int i = 0; i < 12; i++) acc[i] = (f32x4){0.f,0.f,0.f,0.f};
        for (int ks = 0; ks < 6; ks++) {
            __syncthreads();
            #pragma unroll
            for (int i = 0; i < 6; i++) {
                int f = t + 256*i;
                int row = f / 8, ch = (f - row*8) * 4;
                float4 v = *(const float4*)(W + (size_t)row*DIMC + ks*32 + ch);
                __bf16* dst = &Ws[row][ch];
                dst[0] = (__bf16)v.x; dst[1] = (__bf16)v.y; dst[2] = (__bf16)v.z; dst[3] = (__bf16)v.w;
            }
            __syncthreads();
            bf16x8 afrag = *(const bf16x8*)&As[16*wave + lr][ks*32 + 8*lg];
            #pragma unroll
            for (int ct = 0; ct < 12; ct++) {
                bf16x8 bfrag = *(const bf16x8*)&Ws[16*ct + lr][8*lg];
                acc[ct] = mfma16(afrag, bfrag, acc[ct]);
            }
        }
        if (bias) {
            #pragma unroll
            for (int ct = 0; ct < 12; ct++) {
                float bv = bias[16*ct + lr];
                #pragma unroll
                for (int reg = 0; reg < 4; reg++) acc[ct][reg] += bv;
            }
        }
        if (nrm) {
            #pragma unroll
            for (int h = 0; h < HH; h++) {
                float sc = 1.f;
                if (nrm == 2) sc = __expf(fminf(ls[h], 4.6051702f)) * 1.4426950408889634f;
                #pragma unroll
                for (int reg = 0; reg < 4; reg++) {
                    float ss = acc[2*h][reg]*acc[2*h][reg] + acc[2*h+1][reg]*acc[2*h+1][reg];
                    ss += __shfl_xor(ss, 1); ss += __shfl_xor(ss, 2);
                    ss += __shfl_xor(ss, 4); ss += __shfl_xor(ss, 8);
                    float f = sc / fmaxf(sqrtf(ss), 1e-12f);
                    acc[2*h][reg]   *= f;
                    acc[2*h+1][reg] *= f;
                }
            }
        }
        #pragma unroll
        for (int ct = 0; ct < 12; ct++) {
            int c = 16*ct + lr;
            #pragma unroll
            for (int reg = 0; reg < 4; reg++) {
                int r = m0 + 16*wave + 4*lg + reg;
                D[(size_t)r*DIMC + c] = (__bf16)acc[ct][reg];
            }
        }
    }
}

// ---------------- proj GEMM: bf16 in -> f32 out + bias (LDS-staged) ----------------
__global__ __launch_bounds__(256) void gemm_proj(
    const __bf16* __restrict__ A, const float* __restrict__ W,
    const float* __restrict__ bias, float* __restrict__ D)
{
    __shared__ __bf16 As[64][200];
    __shared__ __bf16 Ws[192][40];
    int m0 = blockIdx.x * 64;
    int t  = threadIdx.x;
    #pragma unroll
    for (int i = 0; i < 6; i++) {
        int f = t + 256*i;
        int row = f / 24, ch = (f - row*24) * 8;
        uint4 v = *(const uint4*)(A + (size_t)(m0+row)*DIMC + ch);
        *(uint4*)&As[row][ch] = v;
    }
    int wave = t >> 6, lane = t & 63, lr = lane & 15, lg = lane >> 4;
    f32x4 acc[12];
    #pragma unroll
    for (int i = 0; i < 12; i++) acc[i] = (f32x4){0.f,0.f,0.f,0.f};
    for (int ks = 0; ks < 6; ks++) {
        __syncthreads();
        #pragma unroll
        for (int i = 0; i < 6; i++) {
            int f = t + 256*i;
            int row = f / 8, ch = (f - row*8) * 4;
            float4 v = *(const float4*)(W + (size_t)row*DIMC + ks*32 + ch);
            __bf16* dst = &Ws[row][ch];
            dst[0] = (__bf16)v.x; dst[1] = (__bf16)v.y; dst[2] = (__bf16)v.z; dst[3] = (__bf16)v.w;
        }
        __syncthreads();
        bf16x8 afrag = *(const bf16x8*)&As[16*wave + lr][ks*32 + 8*lg];
        #pragma unroll
        for (int ct = 0; ct < 12; ct++) {
            bf16x8 bfrag = *(const bf16x8*)&Ws[16*ct + lr][8*lg];
            acc[ct] = mfma16(afrag, bfrag, acc[ct]);
        }
    }
    #pragma unroll
    for (int ct = 0; ct < 12; ct++) {
        int c = 16*ct + lr;
        float bv = bias[c];
        #pragma unroll
        for (int reg = 0; reg < 4; reg++) {
            int r = m0 + 16*wave + 4*lg + reg;
            D[(size_t)r*DIMC + c] = acc[ct][reg] + bv;
        }
    }
}

// ---------------- fused attention: 32x32 MFMA, permlane32_swap P-redistribution ----------------
// QK: S = mfma32(K, Q): lane holds col q=lane&31, rows m_off=(reg&3)+8*(reg>>2)+4*hi
// PV: O = mfma32(P_frag, V_frag): P_frag built via cvt_pk + 4x v_permlane32_swap
// V^T LDS: pitch 192 dwords (rows 32-block aligned), dword idx ^= (d&7)<<2 (bijective per row)
__device__ __forceinline__ int vt_us(int d, int m) {   // ushort index
    int dw = (d*192 + (m >> 1)) ^ ((d & 7) << 2);
    return dw*2 + (m & 1);
}
__global__ __launch_bounds__(256, 4) void attn_kernel(
    const __bf16* __restrict__ qb, const __bf16* __restrict__ kb, const __bf16* __restrict__ vb,
    const float* __restrict__ R, const unsigned* __restrict__ mbits,
    __bf16* __restrict__ cross)
{
    __shared__ __bf16 VTs[32*384];   // 24576 B

    int bh = blockIdx.x;
    int b  = bh / HH;
    int h  = bh - b*HH;
    int w  = b & 63;
    int t  = threadIdx.x;

    const __bf16* Kb = kb + ((size_t)b*NN)*DIMC + 32*h;
    const __bf16* Vb = vb + ((size_t)b*NN)*DIMC + 32*h;
    const __bf16* Qb = qb + ((size_t)b*NN)*DIMC + 32*h;

    // stage V^T with XOR swizzle (same mapping used on read)
    for (int idx = t; idx < NN*4; idx += 256) {
        int part = idx / NN;
        int m    = idx - part*NN;
        union { uint4 u; __bf16 e[8]; } vv;
        vv.u = *(const uint4*)(Vb + (size_t)m*DIMC + 8*part);
        #pragma unroll
        for (int j = 0; j < 8; j++) VTs[vt_us(8*part + j, m)] = vv.e[j];
    }
    for (int idx = t; idx < 32*9; idx += 256) {
        int d = idx / 9, m = NN + (idx - d*9);
        VTs[vt_us(d, m)] = (__bf16)0.f;
    }
    __syncthreads();

    int wave = t >> 6, lane = t & 63;
    int l31 = lane & 31, hi = lane >> 5;
    const f32x16 zero16 = {0.f,0.f,0.f,0.f,0.f,0.f,0.f,0.f,0.f,0.f,0.f,0.f,0.f,0.f,0.f,0.f};

    for (int p = wave; p < 11; p += 4) {
        int q0 = 32*p;
        int rq = min(q0 + l31, NN-1);
        bf16x8 qf0 = *(const bf16x8*)(Qb + (size_t)rq*DIMC + 8*hi);        // kd=0
        bf16x8 qf1 = *(const bf16x8*)(Qb + (size_t)rq*DIMC + 16 + 8*hi);   // kd=1
        const float* Rrow = R + ((size_t)h*NN + rq)*352 + 4*hi;
        const unsigned* mp = mbits + ((size_t)(w*NN + rq))*16 + hi*8;
        uint4 mw = *(const uint4*)mp;
        uint2 mx = *(const uint2*)(mp + 4);
        unsigned long long ma = mw.x | ((unsigned long long)mw.y << 32);
        unsigned long long mbq = mw.z | ((unsigned long long)mw.w << 32);
        unsigned long long mc = mx.x | ((unsigned long long)mx.y << 32);

        f32x16 O = zero16;
        float dsum = 0.f;

        // prefetch K rows for ks=0
        bf16x8 kf0 = *(const bf16x8*)(Kb + (size_t)l31*DIMC + 8*hi);
        bf16x8 kf1 = *(const bf16x8*)(Kb + (size_t)l31*DIMC + 16 + 8*hi);

        for (int ks = 0; ks < 11; ks++) {
            // this-iter R loads (consumed after QK MFMAs)
            f32x4 rA = *(const f32x4*)(Rrow + 32*ks);
            f32x4 rB = *(const f32x4*)(Rrow + 32*ks + 8);
            f32x4 rC = *(const f32x4*)(Rrow + 32*ks + 16);
            f32x4 rD = *(const f32x4*)(Rrow + 32*ks + 24);
            // prefetch K for ks+1
            bf16x8 kf0n = kf0, kf1n = kf1;
            if (ks < 10) {
                int krn = min(32*(ks+1) + l31, NN-1);
                kf0n = *(const bf16x8*)(Kb + (size_t)krn*DIMC + 8*hi);
                kf1n = *(const bf16x8*)(Kb + (size_t)krn*DIMC + 16 + 8*hi);
            }

            f32x16 s = mfma32(kf0, qf0, zero16);
            s = mfma32(kf1, qf1, s);

            unsigned bits = (unsigned)(ma & 0xFFFFu);
            ma = (ma >> 16) | (mbq << 48); mbq = (mbq >> 16) | (mc << 48); mc >>= 16;

            float pv[16];
            #pragma unroll
            for (int r = 0; r < 4; r++) {
                pv[r]    = (bits & (1u << r))      ? __builtin_amdgcn_exp2f(s[r])    * rA[r] : 0.f;
                pv[4+r]  = (bits & (1u << (4+r)))  ? __builtin_amdgcn_exp2f(s[4+r])  * rB[r] : 0.f;
                pv[8+r]  = (bits & (1u << (8+r)))  ? __builtin_amdgcn_exp2f(s[8+r])  * rC[r] : 0.f;
                pv[12+r] = (bits & (1u << (12+r))) ? __builtin_amdgcn_exp2f(s[12+r]) * rD[r] : 0.f;
            }
            // dsum tree
            {
                float t0 = pv[0]+pv[1], t1 = pv[2]+pv[3], t2 = pv[4]+pv[5], t3 = pv[6]+pv[7];
                float t4 = pv[8]+pv[9], t5 = pv[10]+pv[11], t6 = pv[12]+pv[13], t7 = pv[14]+pv[15];
                dsum += ((t0+t1)+(t2+t3)) + ((t4+t5)+(t6+t7));
            }
            // pack + permlane redistribution (C layout -> A layout)
            unsigned w0 = pack2(pv[0],  pv[1]),  w1 = pack2(pv[2],  pv[3]);
            unsigned w2 = pack2(pv[4],  pv[5]),  w3 = pack2(pv[6],  pv[7]);
            unsigned w4 = pack2(pv[8],  pv[9]),  w5 = pack2(pv[10], pv[11]);
            unsigned w6 = pack2(pv[12], pv[13]), w7 = pack2(pv[14], pv[15]);
            pl32_swap(w0, w2); pl32_swap(w1, w3);
            pl32_swap(w4, w6); pl32_swap(w5, w7);
            union { unsigned u[4]; bf16x8 f; } fa, fb;
            fa.u[0] = w0; fa.u[1] = w1; fa.u[2] = w2; fa.u[3] = w3;   // k-block m [32ks, +16)
            fb.u[0] = w4; fb.u[1] = w5; fb.u[2] = w6; fb.u[3] = w7;   // k-block m [32ks+16, +16)

            int mv0 = 32*ks + 8*hi;
            bf16x8 v0 = *(const bf16x8*)&VTs[vt_us(l31, mv0)];
            bf16x8 v1 = *(const bf16x8*)&VTs[vt_us(l31, mv0 + 16)];
            O = mfma32(fa.f, v0, O);
            O = mfma32(fb.f, v1, O);

            kf0 = kf0n; kf1 = kf1n;
        }

        dsum += __shfl_xor(dsum, 32);
        float dinv = 1.f / dsum;

        #pragma unroll
        for (int r = 0; r < 16; r++) {
            int off = (r & 3) + 8*(r >> 2) + 4*hi;
            float dv = __shfl(dinv, off);
            int qr = q0 + off;
            if (qr < NN)
                cross[((size_t)b*NN + qr)*DIMC + 32*h + l31] = (__bf16)(O[r] * dv);
        }
    }
}

extern "C" void kernel_launch(void* const* d_in, const int* in_sizes, int n_in,
                              void* d_out, int out_size, void* d_ws, size_t ws_size,
                              hipStream_t stream) {
    const float* x           = (const float*)d_in[0];
    const float* y           = (const float*)d_in[1];
    const float* mask        = (const float*)d_in[2];
    const float* qkv1_w      = (const float*)d_in[3];
    const float* qkv2_w      = (const float*)d_in[4];
    const float* v1_bias     = (const float*)d_in[6];
    const float* q2_bias     = (const float*)d_in[7];
    const float* logit_scale = (const float*)d_in[9];
    const float* cpb_w1      = (const float*)d_in[10];
    const float* cpb_b1      = (const float*)d_in[11];
    const float* cpb_w2      = (const float*)d_in[12];
    const float* proj_w      = (const float*)d_in[13];
    const float* proj_b      = (const float*)d_in[14];
    const float* rel_table   = (const float*)d_in[15];
    const int*   rp_index    = (const int*)d_in[16];

    char* ws = (char*)d_ws;
    float*    table  = (float*)(ws + OFF_TABLE);
    float*    R      = (float*)(ws + OFF_R);
    unsigned* mb     = (unsigned*)(ws + OFF_MB);
    __bf16*   q_bf   = (__bf16*)(ws + OFF_QB);
    __bf16*   k_bf   = (__bf16*)(ws + OFF_KB);
    __bf16*   v_bf   = (__bf16*)(ws + OFF_VB);
    __bf16*   crossb = (__bf16*)(ws + OFF_CROSS);

    cpb_table_kernel<<<2197, 256, 0, stream>>>(rel_table, cpb_w1, cpb_b1, cpb_w2, table);
    r_kernel<<<(HH*NN*352 + 255)/256, 256, 0, stream>>>(table, rp_index, R);
    mbits2_kernel<<<(64*NN*2 + 255)/256, 256, 0, stream>>>(mask, mb);
    // x -> k (norm, no bias), v (+v1_bias, no norm)
    gemm_f32in<<<MM/64, 256, 0, stream>>>(x, logit_scale,
                                          qkv1_w + 192*192, nullptr, 1, k_bf,
                                          qkv1_w + 384*192, v1_bias, 0, v_bf);
    // y -> q (+q2_bias, norm+scale*log2e)
    gemm_f32in<<<MM/64, 256, 0, stream>>>(y, logit_scale,
                                          qkv2_w, q2_bias, 2, q_bf,
                                          nullptr, nullptr, 0, nullptr);

    attn_kernel<<<BB*HH, 256, 0, stream>>>(q_bf, k_bf, v_bf, R, mb, crossb);

    gemm_proj<<<MM/64, 256, 0, stream>>>(crossb, proj_w, proj_b, (float*)d_out);
}

// Round 9
// 585.973 us; speedup vs baseline: 1.4120x; 1.0791x over previous
//
#include <hip/hip_runtime.h>

#define HH   6
#define NN   343
#define BB   512
#define DIMC 192
#define MM   (BB*NN)      // 175616

// workspace offsets (bytes)
#define OFF_TABLE 0                        // [2197][8] f32
#define OFF_R     70400                    // [6][343][352] f32  (exp(rpb-26), zero tail)
#define OFF_MB    2968064                  // [64*343][16] u32   (bit-packed mask, 32x32-reg order)
#define OFF_QB    4372992                  // [M][192] bf16 (normalized * scale * log2e)
#define OFF_KB    (OFF_QB + 67436544)      // [M][192] bf16 (normalized)
#define OFF_VB    (OFF_KB + 67436544)
#define OFF_CROSS (OFF_VB + 67436544)
#define OFF_WB    (OFF_CROSS + 67436544)   // [1344][192] bf16: qkv1(576), qkv2(576), proj(192)
// end = 274,635,264 bytes

typedef __bf16 bf16x8 __attribute__((ext_vector_type(8)));
typedef float  f32x4  __attribute__((ext_vector_type(4)));
typedef float  f32x16 __attribute__((ext_vector_type(16)));

__device__ __forceinline__ f32x4 mfma16(bf16x8 a, bf16x8 b, f32x4 c) {
    return __builtin_amdgcn_mfma_f32_16x16x32_bf16(a, b, c, 0, 0, 0);
}
__device__ __forceinline__ f32x16 mfma32(bf16x8 a, bf16x8 b, f32x16 c) {
    return __builtin_amdgcn_mfma_f32_32x32x16_bf16(a, b, c, 0, 0, 0);
}

__device__ __forceinline__ unsigned pack2(float a, float b) {
    union { __bf16 h[2]; unsigned u; } x;
    x.h[0] = (__bf16)a; x.h[1] = (__bf16)b;
    return x.u;
}
// swaps a[32:63] <-> b[0:31]
__device__ __forceinline__ void pl32_swap(unsigned &a, unsigned &b) {
    asm volatile("v_permlane32_swap_b32 %0, %1" : "+v"(a), "+v"(b));
}

// ---------------- K1: CPB MLP -> table[2197][8] ----------------
__global__ __launch_bounds__(256) void cpb_table_kernel(
    const float* __restrict__ rel_table, const float* __restrict__ w1,
    const float* __restrict__ b1, const float* __restrict__ w2,
    float* __restrict__ table)
{
    int i = blockIdx.x;
    int t = threadIdx.x;
    float t0 = rel_table[i*3+0], t1 = rel_table[i*3+1], t2 = rel_table[i*3+2];
    float acc[HH];
    #pragma unroll
    for (int h = 0; h < HH; h++) acc[h] = 0.f;
    for (int j = t; j < 512; j += 256) {
        float hv = w1[j*3+0]*t0 + w1[j*3+1]*t1 + w1[j*3+2]*t2 + b1[j];
        hv = fmaxf(hv, 0.f);
        #pragma unroll
        for (int h = 0; h < HH; h++) acc[h] += w2[h*512+j] * hv;
    }
    __shared__ float red[256*HH];
    #pragma unroll
    for (int h = 0; h < HH; h++) red[t*HH+h] = acc[h];
    __syncthreads();
    for (int s = 128; s > 0; s >>= 1) {
        if (t < s) {
            #pragma unroll
            for (int h = 0; h < HH; h++) red[t*HH+h] += red[(t+s)*HH+h];
        }
        __syncthreads();
    }
    if (t < HH) table[(size_t)i*8 + t] = red[t];
}

// ---------------- K2: R = exp(16*sigmoid(gather) - 26), [6][343][352] ----------------
__global__ __launch_bounds__(256) void r_kernel(
    const float* __restrict__ table, const int* __restrict__ rp_index,
    float* __restrict__ R)
{
    int id = blockIdx.x*256 + threadIdx.x;
    if (id >= HH*NN*352) return;
    int h   = id / (NN*352);
    int rem = id - h*(NN*352);
    int n   = rem / 352;
    int mc  = rem - n*352;
    float out = 0.f;
    if (mc < NN) {
        float v = table[(size_t)rp_index[n*NN+mc]*8 + h];
        float r = 16.f / (1.f + __expf(-v));
        out = __expf(r - 26.f);
    }
    R[id] = out;
}

// ---------------- K3: bit-pack mask for 32x32 reg order ----------------
__global__ __launch_bounds__(256) void mbits2_kernel(
    const float* __restrict__ mask, unsigned* __restrict__ mb)
{
    int id = blockIdx.x*256 + threadIdx.x;    // 64*343*2 threads
    if (id >= 64*NN*2) return;
    int hi  = id & 1;
    int row = id >> 1;                         // w*343 + n
    const float* mrow = mask + (size_t)row*NN;
    unsigned* out = mb + (size_t)row*16 + hi*8;
    #pragma unroll
    for (int wd = 0; wd < 6; wd++) {
        unsigned u = 0;
        #pragma unroll
        for (int p = 0; p < 32; p++) {
            int g = 32*wd + p;
            int ks = g >> 4, r = g & 15;
            int m = 32*ks + (r&3) + 8*(r>>2) + 4*hi;
            if (m < NN && mrow[m] > -50.f) u |= (1u << p);
        }
        out[wd] = u;
    }
    out[6] = 0u; out[7] = 0u;
}

// ---------------- K4: convert weights f32 -> bf16 (qkv1 | qkv2 | proj) ----------------
__global__ __launch_bounds__(256) void wcvt_kernel(
    const float* __restrict__ qkv1, const float* __restrict__ qkv2,
    const float* __restrict__ proj, __bf16* __restrict__ out)
{
    int i = blockIdx.x*256 + threadIdx.x;   // float4 index
    const int n1 = 110592/4, n2 = 221184/4, n3 = 258048/4;
    if (i >= n3) return;
    const float* src; int off;
    if (i < n1)      { src = qkv1; off = i; }
    else if (i < n2) { src = qkv2; off = i - n1; }
    else             { src = proj; off = i - n2; }
    float4 v = ((const float4*)src)[off];
    __bf16* d = out + (size_t)i*4;
    d[0] = (__bf16)v.x; d[1] = (__bf16)v.y; d[2] = (__bf16)v.z; d[3] = (__bf16)v.w;
}

// ---------------- GEMM v3: f32 A direct-from-global, bf16 W staged in LDS, 2 phases ----------------
// norm: 0 = none, 1 = k-norm (1/|k|), 2 = q-norm (scale*log2e/|q|)
__global__ __launch_bounds__(256) void gemm_f32in(
    const float* __restrict__ A, const float* __restrict__ ls,
    const __bf16* __restrict__ W0, const float* __restrict__ bias0, int norm0, __bf16* __restrict__ D0,
    const __bf16* __restrict__ W1, const float* __restrict__ bias1, int norm1, __bf16* __restrict__ D1)
{
    __shared__ __bf16 Ws[192*40];
    int m0 = blockIdx.x * 64;
    int t  = threadIdx.x;
    int wave = t >> 6, lane = t & 63, lr = lane & 15, lg = lane >> 4;
    int r = m0 + 16*wave + lr;

    // A row fragments, f32 -> bf16, kept in regs across phases
    bf16x8 afr[6];
    #pragma unroll
    for (int ks = 0; ks < 6; ks++) {
        const float* ap = A + (size_t)r*DIMC + 32*ks + 8*lg;
        float4 v0 = *(const float4*)ap;
        float4 v1 = *(const float4*)(ap + 4);
        bf16x8 f;
        f[0]=(__bf16)v0.x; f[1]=(__bf16)v0.y; f[2]=(__bf16)v0.z; f[3]=(__bf16)v0.w;
        f[4]=(__bf16)v1.x; f[5]=(__bf16)v1.y; f[6]=(__bf16)v1.z; f[7]=(__bf16)v1.w;
        afr[ks] = f;
    }

    #pragma unroll 1
    for (int phase = 0; phase < 2; phase++) {
        const __bf16* W    = phase ? W1 : W0;
        if (!W) break;
        const float* bias  = phase ? bias1 : bias0;
        int          nrm   = phase ? norm1 : norm0;
        __bf16*      D     = phase ? D1 : D0;
        f32x4 acc[12];
        #pragma unroll
        for (int i = 0; i < 12; i++) acc[i] = (f32x4){0.f,0.f,0.f,0.f};
        for (int ks = 0; ks < 6; ks++) {
            __syncthreads();
            #pragma unroll
            for (int i = 0; i < 3; i++) {
                int c = t + 256*i;         // 768 uint4 chunks = 192 rows x 4 col-groups
                int row = c >> 2, cg = c & 3;
                uint4 v = *(const uint4*)(W + (size_t)row*DIMC + 32*ks + 8*cg);
                *(uint4*)&Ws[row*40 + 8*cg] = v;
            }
            __syncthreads();
            #pragma unroll
            for (int ct = 0; ct < 12; ct++) {
                bf16x8 bfrag = *(const bf16x8*)&Ws[(16*ct + lr)*40 + 8*lg];
                acc[ct] = mfma16(afr[ks], bfrag, acc[ct]);
            }
        }
        if (bias) {
            #pragma unroll
            for (int ct = 0; ct < 12; ct++) {
                float bv = bias[16*ct + lr];
                #pragma unroll
                for (int reg = 0; reg < 4; reg++) acc[ct][reg] += bv;
            }
        }
        if (nrm) {
            #pragma unroll
            for (int h = 0; h < HH; h++) {
                float sc = 1.f;
                if (nrm == 2) sc = __expf(fminf(ls[h], 4.6051702f)) * 1.4426950408889634f;
                #pragma unroll
                for (int reg = 0; reg < 4; reg++) {
                    float ss = acc[2*h][reg]*acc[2*h][reg] + acc[2*h+1][reg]*acc[2*h+1][reg];
                    ss += __shfl_xor(ss, 1); ss += __shfl_xor(ss, 2);
                    ss += __shfl_xor(ss, 4); ss += __shfl_xor(ss, 8);
                    float f = sc / fmaxf(sqrtf(ss), 1e-12f);
                    acc[2*h][reg]   *= f;
                    acc[2*h+1][reg] *= f;
                }
            }
        }
        #pragma unroll
        for (int ct = 0; ct < 12; ct++) {
            int c = 16*ct + lr;
            #pragma unroll
            for (int reg = 0; reg < 4; reg++) {
                int row = m0 + 16*wave + 4*lg + reg;
                D[(size_t)row*DIMC + c] = (__bf16)acc[ct][reg];
            }
        }
    }
}

// ---------------- proj GEMM v3: bf16 A direct, bf16 W staged in LDS, f32 out + bias ----------------
__global__ __launch_bounds__(256) void gemm_proj(
    const __bf16* __restrict__ A, const __bf16* __restrict__ W,
    const float* __restrict__ bias, float* __restrict__ D)
{
    __shared__ __bf16 Ws[192*40];
    int m0 = blockIdx.x * 64;
    int t  = threadIdx.x;
    int wave = t >> 6, lane = t & 63, lr = lane & 15, lg = lane >> 4;
    int r = m0 + 16*wave + lr;

    bf16x8 afr[6];
    #pragma unroll
    for (int ks = 0; ks < 6; ks++)
        afr[ks] = *(const bf16x8*)(A + (size_t)r*DIMC + 32*ks + 8*lg);

    f32x4 acc[12];
    #pragma unroll
    for (int i = 0; i < 12; i++) acc[i] = (f32x4){0.f,0.f,0.f,0.f};
    for (int ks = 0; ks < 6; ks++) {
        __syncthreads();
        #pragma unroll
        for (int i = 0; i < 3; i++) {
            int c = t + 256*i;
            int row = c >> 2, cg = c & 3;
            uint4 v = *(const uint4*)(W + (size_t)row*DIMC + 32*ks + 8*cg);
            *(uint4*)&Ws[row*40 + 8*cg] = v;
        }
        __syncthreads();
        #pragma unroll
        for (int ct = 0; ct < 12; ct++) {
            bf16x8 bfrag = *(const bf16x8*)&Ws[(16*ct + lr)*40 + 8*lg];
            acc[ct] = mfma16(afr[ks], bfrag, acc[ct]);
        }
    }
    #pragma unroll
    for (int ct = 0; ct < 12; ct++) {
        int c = 16*ct + lr;
        float bv = bias[c];
        #pragma unroll
        for (int reg = 0; reg < 4; reg++) {
            int row = m0 + 16*wave + 4*lg + reg;
            D[(size_t)row*DIMC + c] = acc[ct][reg] + bv;
        }
    }
}

// ---------------- fused attention: 32x32 MFMA, permlane P-redistribution, unrolled ks ----------------
// QK: S = mfma32(K, Q): lane holds col q=lane&31, rows m_off=(reg&3)+8*(reg>>2)+4*hi
// V^T LDS: linear pitch 360 ushorts (180 dwords == 20 mod 32 -> uniform 2/bank on b128 reads)
#define VT_PITCH 360
__global__ __launch_bounds__(256, 4) void attn_kernel(
    const __bf16* __restrict__ qb, const __bf16* __restrict__ kb, const __bf16* __restrict__ vb,
    const float* __restrict__ R, const unsigned* __restrict__ mbits,
    __bf16* __restrict__ cross)
{
    __shared__ __bf16 VTs[32*VT_PITCH];   // 23040 B

    int bh = blockIdx.x;
    int b  = bh / HH;
    int h  = bh - b*HH;
    int w  = b & 63;
    int t  = threadIdx.x;

    const __bf16* Kb = kb + ((size_t)b*NN)*DIMC + 32*h;
    const __bf16* Vb = vb + ((size_t)b*NN)*DIMC + 32*h;
    const __bf16* Qb = qb + ((size_t)b*NN)*DIMC + 32*h;

    // stage V^T (consecutive threads -> consecutive m)
    for (int idx = t; idx < NN*4; idx += 256) {
        int part = idx / NN;
        int m    = idx - part*NN;
        union { uint4 u; __bf16 e[8]; } vv;
        vv.u = *(const uint4*)(Vb + (size_t)m*DIMC + 8*part);
        #pragma unroll
        for (int j = 0; j < 8; j++) VTs[(8*part + j)*VT_PITCH + m] = vv.e[j];
    }
    for (int idx = t; idx < 32*9; idx += 256) {
        int d = idx / 9, m = NN + (idx - d*9);
        VTs[d*VT_PITCH + m] = (__bf16)0.f;
    }
    __syncthreads();

    int wave = t >> 6, lane = t & 63;
    int l31 = lane & 31, hi = lane >> 5;
    const f32x16 zero16 = {0.f,0.f,0.f,0.f,0.f,0.f,0.f,0.f,0.f,0.f,0.f,0.f,0.f,0.f,0.f,0.f};
    const __bf16* VTl = VTs + (size_t)l31*VT_PITCH;   // per-lane V row base

    for (int p = wave; p < 11; p += 4) {
        int q0 = 32*p;
        int rq = min(q0 + l31, NN-1);
        bf16x8 qf0 = *(const bf16x8*)(Qb + (size_t)rq*DIMC + 8*hi);        // kd 0..15
        bf16x8 qf1 = *(const bf16x8*)(Qb + (size_t)rq*DIMC + 16 + 8*hi);   // kd 16..31
        const float* Rrow = R + ((size_t)h*NN + rq)*352 + 4*hi;
        const unsigned* mp = mbits + ((size_t)(w*NN + rq))*16 + hi*8;
        uint4 mw = *(const uint4*)mp;
        uint2 mx = *(const uint2*)(mp + 4);
        const unsigned mkw[6] = {mw.x, mw.y, mw.z, mw.w, mx.x, mx.y};

        f32x16 O = zero16;
        float dsum = 0.f;

        // prefetch K rows for ks=0
        bf16x8 kf0 = *(const bf16x8*)(Kb + (size_t)l31*DIMC + 8*hi);
        bf16x8 kf1 = *(const bf16x8*)(Kb + (size_t)l31*DIMC + 16 + 8*hi);

        #pragma unroll
        for (int ks = 0; ks < 11; ks++) {
            // this-iter R loads (consumed after QK MFMAs); addresses fold to imm offsets
            f32x4 rA = *(const f32x4*)(Rrow + 32*ks);
            f32x4 rB = *(const f32x4*)(Rrow + 32*ks + 8);
            f32x4 rC = *(const f32x4*)(Rrow + 32*ks + 16);
            f32x4 rD = *(const f32x4*)(Rrow + 32*ks + 24);
            // prefetch K for ks+1
            bf16x8 kf0n = kf0, kf1n = kf1;
            if (ks < 10) {
                int krn = min(32*(ks+1) + l31, NN-1);
                kf0n = *(const bf16x8*)(Kb + (size_t)krn*DIMC + 8*hi);
                kf1n = *(const bf16x8*)(Kb + (size_t)krn*DIMC + 16 + 8*hi);
            }

            f32x16 s = mfma32(kf0, qf0, zero16);
            s = mfma32(kf1, qf1, s);

            // static mask extraction (loop fully unrolled)
            unsigned word = mkw[ks >> 1];
            unsigned bits = (ks & 1) ? (word >> 16) : (word & 0xFFFFu);

            float pv[16];
            #pragma unroll
            for (int r = 0; r < 4; r++) {
                pv[r]    = (bits & (1u << r))      ? __builtin_amdgcn_exp2f(s[r])    * rA[r] : 0.f;
                pv[4+r]  = (bits & (1u << (4+r)))  ? __builtin_amdgcn_exp2f(s[4+r])  * rB[r] : 0.f;
                pv[8+r]  = (bits & (1u << (8+r)))  ? __builtin_amdgcn_exp2f(s[8+r])  * rC[r] : 0.f;
                pv[12+r] = (bits & (1u << (12+r))) ? __builtin_amdgcn_exp2f(s[12+r]) * rD[r] : 0.f;
            }
            {
                float t0 = pv[0]+pv[1], t1 = pv[2]+pv[3], t2 = pv[4]+pv[5], t3 = pv[6]+pv[7];
                float t4 = pv[8]+pv[9], t5 = pv[10]+pv[11], t6 = pv[12]+pv[13], t7 = pv[14]+pv[15];
                dsum += ((t0+t1)+(t2+t3)) + ((t4+t5)+(t6+t7));
            }
            // pack + permlane redistribution (C layout -> A layout)
            unsigned w0 = pack2(pv[0],  pv[1]),  w1 = pack2(pv[2],  pv[3]);
            unsigned w2 = pack2(pv[4],  pv[5]),  w3 = pack2(pv[6],  pv[7]);
            unsigned w4 = pack2(pv[8],  pv[9]),  w5 = pack2(pv[10], pv[11]);
            unsigned w6 = pack2(pv[12], pv[13]), w7 = pack2(pv[14], pv[15]);
            pl32_swap(w0, w2); pl32_swap(w1, w3);
            pl32_swap(w4, w6); pl32_swap(w5, w7);
            union { unsigned u[4]; bf16x8 f; } fa, fb;
            fa.u[0] = w0; fa.u[1] = w1; fa.u[2] = w2; fa.u[3] = w3;   // m in [32ks, 32ks+16)
            fb.u[0] = w4; fb.u[1] = w5; fb.u[2] = w6; fb.u[3] = w7;   // m in [32ks+16, 32ks+32)

            bf16x8 v0 = *(const bf16x8*)&VTl[32*ks + 8*hi];
            bf16x8 v1 = *(const bf16x8*)&VTl[32*ks + 16 + 8*hi];
            O = mfma32(fa.f, v0, O);
            O = mfma32(fb.f, v1, O);

            kf0 = kf0n; kf1 = kf1n;
        }

        dsum += __shfl_xor(dsum, 32);
        float dinv = 1.f / dsum;

        #pragma unroll
        for (int r = 0; r < 16; r++) {
            int off = (r & 3) + 8*(r >> 2) + 4*hi;
            float dv = __shfl(dinv, off);
            int qr = q0 + off;
            if (qr < NN)
                cross[((size_t)b*NN + qr)*DIMC + 32*h + l31] = (__bf16)(O[r] * dv);
        }
    }
}

extern "C" void kernel_launch(void* const* d_in, const int* in_sizes, int n_in,
                              void* d_out, int out_size, void* d_ws, size_t ws_size,
                              hipStream_t stream) {
    const float* x           = (const float*)d_in[0];
    const float* y           = (const float*)d_in[1];
    const float* mask        = (const float*)d_in[2];
    const float* qkv1_w      = (const float*)d_in[3];
    const float* qkv2_w      = (const float*)d_in[4];
    const float* v1_bias     = (const float*)d_in[6];
    const float* q2_bias     = (const float*)d_in[7];
    const float* logit_scale = (const float*)d_in[9];
    const float* cpb_w1      = (const float*)d_in[10];
    const float* cpb_b1      = (const float*)d_in[11];
    const float* cpb_w2      = (const float*)d_in[12];
    const float* proj_w      = (const float*)d_in[13];
    const float* proj_b      = (const float*)d_in[14];
    const float* rel_table   = (const float*)d_in[15];
    const int*   rp_index    = (const int*)d_in[16];

    char* ws = (char*)d_ws;
    float*    table  = (float*)(ws + OFF_TABLE);
    float*    R      = (float*)(ws + OFF_R);
    unsigned* mb     = (unsigned*)(ws + OFF_MB);
    __bf16*   q_bf   = (__bf16*)(ws + OFF_QB);
    __bf16*   k_bf   = (__bf16*)(ws + OFF_KB);
    __bf16*   v_bf   = (__bf16*)(ws + OFF_VB);
    __bf16*   crossb = (__bf16*)(ws + OFF_CROSS);
    __bf16*   wbf    = (__bf16*)(ws + OFF_WB);

    __bf16* w_k    = wbf + 192*DIMC;        // qkv1 rows 192..383
    __bf16* w_v    = wbf + 384*DIMC;        // qkv1 rows 384..575
    __bf16* w_q    = wbf + 576*DIMC;        // qkv2 rows 0..191
    __bf16* w_proj = wbf + 1152*DIMC;

    cpb_table_kernel<<<2197, 256, 0, stream>>>(rel_table, cpb_w1, cpb_b1, cpb_w2, table);
    r_kernel<<<(HH*NN*352 + 255)/256, 256, 0, stream>>>(table, rp_index, R);
    mbits2_kernel<<<(64*NN*2 + 255)/256, 256, 0, stream>>>(mask, mb);
    wcvt_kernel<<<(258048/4 + 255)/256, 256, 0, stream>>>(qkv1_w, qkv2_w, proj_w, wbf);
    // x -> k (norm, no bias), v (+v1_bias, no norm)
    gemm_f32in<<<MM/64, 256, 0, stream>>>(x, logit_scale,
                                          w_k, nullptr, 1, k_bf,
                                          w_v, v1_bias, 0, v_bf);
    // y -> q (+q2_bias, norm+scale*log2e)
    gemm_f32in<<<MM/64, 256, 0, stream>>>(y, logit_scale,
                                          w_q, q2_bias, 2, q_bf,
                                          nullptr, nullptr, 0, nullptr);

    attn_kernel<<<BB*HH, 256, 0, stream>>>(q_bf, k_bf, v_bf, R, mb, crossb);

    gemm_proj<<<MM/64, 256, 0, stream>>>(crossb, w_proj, proj_b, (float*)d_out);
}

// Round 11
// 544.073 us; speedup vs baseline: 1.5208x; 1.0770x over previous
//
#include <hip/hip_runtime.h>

#define HH   6
#define NN   343
#define BB   512
#define DIMC 192
#define MM   (BB*NN)      // 175616

// workspace offsets (bytes)
#define OFF_TABLE 0                        // [2197][8] f32
#define OFF_R     70400                    // [6][343][352] f32  (exp(rpb-26), zero tail)
#define OFF_MB    2968064                  // [64*343][16] u32   (bit-packed mask, 32x32-reg order)
#define OFF_QB    4372992                  // [M][192] bf16 (normalized * scale * log2e)
#define OFF_KB    (OFF_QB + 67436544)      // [M][192] bf16 (normalized)
#define OFF_VB    (OFF_KB + 67436544)
#define OFF_CROSS (OFF_VB + 67436544)
#define OFF_WB    (OFF_CROSS + 67436544)   // [1344][192] bf16: qkv1(576), qkv2(576), proj(192)
// end = 274,635,264 bytes

typedef __bf16 bf16x8 __attribute__((ext_vector_type(8)));
typedef float  f32x4  __attribute__((ext_vector_type(4)));
typedef float  f32x16 __attribute__((ext_vector_type(16)));

__device__ __forceinline__ f32x4 mfma16(bf16x8 a, bf16x8 b, f32x4 c) {
    return __builtin_amdgcn_mfma_f32_16x16x32_bf16(a, b, c, 0, 0, 0);
}
__device__ __forceinline__ f32x16 mfma32(bf16x8 a, bf16x8 b, f32x16 c) {
    return __builtin_amdgcn_mfma_f32_32x32x16_bf16(a, b, c, 0, 0, 0);
}

__device__ __forceinline__ unsigned pack2(float a, float b) {
    union { __bf16 h[2]; unsigned u; } x;
    x.h[0] = (__bf16)a; x.h[1] = (__bf16)b;
    return x.u;
}
// swaps a[32:63] <-> b[0:31]
__device__ __forceinline__ void pl32_swap(unsigned &a, unsigned &b) {
    asm volatile("v_permlane32_swap_b32 %0, %1" : "+v"(a), "+v"(b));
}

// ---------------- K1: CPB MLP -> table[2197][8] ----------------
__global__ __launch_bounds__(256) void cpb_table_kernel(
    const float* __restrict__ rel_table, const float* __restrict__ w1,
    const float* __restrict__ b1, const float* __restrict__ w2,
    float* __restrict__ table)
{
    int i = blockIdx.x;
    int t = threadIdx.x;
    float t0 = rel_table[i*3+0], t1 = rel_table[i*3+1], t2 = rel_table[i*3+2];
    float acc[HH];
    #pragma unroll
    for (int h = 0; h < HH; h++) acc[h] = 0.f;
    for (int j = t; j < 512; j += 256) {
        float hv = w1[j*3+0]*t0 + w1[j*3+1]*t1 + w1[j*3+2]*t2 + b1[j];
        hv = fmaxf(hv, 0.f);
        #pragma unroll
        for (int h = 0; h < HH; h++) acc[h] += w2[h*512+j] * hv;
    }
    __shared__ float red[256*HH];
    #pragma unroll
    for (int h = 0; h < HH; h++) red[t*HH+h] = acc[h];
    __syncthreads();
    for (int s = 128; s > 0; s >>= 1) {
        if (t < s) {
            #pragma unroll
            for (int h = 0; h < HH; h++) red[t*HH+h] += red[(t+s)*HH+h];
        }
        __syncthreads();
    }
    if (t < HH) table[(size_t)i*8 + t] = red[t];
}

// ---------------- K2: R = exp(16*sigmoid(gather) - 26), [6][343][352] ----------------
__global__ __launch_bounds__(256) void r_kernel(
    const float* __restrict__ table, const int* __restrict__ rp_index,
    float* __restrict__ R)
{
    int id = blockIdx.x*256 + threadIdx.x;
    if (id >= HH*NN*352) return;
    int h   = id / (NN*352);
    int rem = id - h*(NN*352);
    int n   = rem / 352;
    int mc  = rem - n*352;
    float out = 0.f;
    if (mc < NN) {
        float v = table[(size_t)rp_index[n*NN+mc]*8 + h];
        float r = 16.f / (1.f + __expf(-v));
        out = __expf(r - 26.f);
    }
    R[id] = out;
}

// ---------------- K3: bit-pack mask for 32x32 reg order ----------------
__global__ __launch_bounds__(256) void mbits2_kernel(
    const float* __restrict__ mask, unsigned* __restrict__ mb)
{
    int id = blockIdx.x*256 + threadIdx.x;    // 64*343*2 threads
    if (id >= 64*NN*2) return;
    int hi  = id & 1;
    int row = id >> 1;                         // w*343 + n
    const float* mrow = mask + (size_t)row*NN;
    unsigned* out = mb + (size_t)row*16 + hi*8;
    #pragma unroll
    for (int wd = 0; wd < 6; wd++) {
        unsigned u = 0;
        #pragma unroll
        for (int p = 0; p < 32; p++) {
            int g = 32*wd + p;
            int ks = g >> 4, r = g & 15;
            int m = 32*ks + (r&3) + 8*(r>>2) + 4*hi;
            if (m < NN && mrow[m] > -50.f) u |= (1u << p);
        }
        out[wd] = u;
    }
    out[6] = 0u; out[7] = 0u;
}

// ---------------- K4: convert weights f32 -> bf16 (qkv1 | qkv2 | proj) ----------------
__global__ __launch_bounds__(256) void wcvt_kernel(
    const float* __restrict__ qkv1, const float* __restrict__ qkv2,
    const float* __restrict__ proj, __bf16* __restrict__ out)
{
    int i = blockIdx.x*256 + threadIdx.x;   // float4 index
    const int n1 = 110592/4, n2 = 221184/4, n3 = 258048/4;
    if (i >= n3) return;
    const float* src; int off;
    if (i < n1)      { src = qkv1; off = i; }
    else if (i < n2) { src = qkv2; off = i - n1; }
    else             { src = proj; off = i - n2; }
    float4 v = ((const float4*)src)[off];
    __bf16* d = out + (size_t)i*4;
    d[0] = (__bf16)v.x; d[1] = (__bf16)v.y; d[2] = (__bf16)v.z; d[3] = (__bf16)v.w;
}

// ---------------- GEMM v3: f32 A direct-from-global, bf16 W staged in LDS, 2 phases ----------------
// norm: 0 = none, 1 = k-norm (1/|k|), 2 = q-norm (scale*log2e/|q|)
__global__ __launch_bounds__(256) void gemm_f32in(
    const float* __restrict__ A, const float* __restrict__ ls,
    const __bf16* __restrict__ W0, const float* __restrict__ bias0, int norm0, __bf16* __restrict__ D0,
    const __bf16* __restrict__ W1, const float* __restrict__ bias1, int norm1, __bf16* __restrict__ D1)
{
    __shared__ __bf16 Ws[192*40];
    int m0 = blockIdx.x * 64;
    int t  = threadIdx.x;
    int wave = t >> 6, lane = t & 63, lr = lane & 15, lg = lane >> 4;
    int r = m0 + 16*wave + lr;

    // A row fragments, f32 -> bf16, kept in regs across phases
    bf16x8 afr[6];
    #pragma unroll
    for (int ks = 0; ks < 6; ks++) {
        const float* ap = A + (size_t)r*DIMC + 32*ks + 8*lg;
        float4 v0 = *(const float4*)ap;
        float4 v1 = *(const float4*)(ap + 4);
        bf16x8 f;
        f[0]=(__bf16)v0.x; f[1]=(__bf16)v0.y; f[2]=(__bf16)v0.z; f[3]=(__bf16)v0.w;
        f[4]=(__bf16)v1.x; f[5]=(__bf16)v1.y; f[6]=(__bf16)v1.z; f[7]=(__bf16)v1.w;
        afr[ks] = f;
    }

    #pragma unroll 1
    for (int phase = 0; phase < 2; phase++) {
        const __bf16* W    = phase ? W1 : W0;
        if (!W) break;
        const float* bias  = phase ? bias1 : bias0;
        int          nrm   = phase ? norm1 : norm0;
        __bf16*      D     = phase ? D1 : D0;
        f32x4 acc[12];
        #pragma unroll
        for (int i = 0; i < 12; i++) acc[i] = (f32x4){0.f,0.f,0.f,0.f};
        for (int ks = 0; ks < 6; ks++) {
            __syncthreads();
            #pragma unroll
            for (int i = 0; i < 3; i++) {
                int c = t + 256*i;         // 768 uint4 chunks = 192 rows x 4 col-groups
                int row = c >> 2, cg = c & 3;
                uint4 v = *(const uint4*)(W + (size_t)row*DIMC + 32*ks + 8*cg);
                *(uint4*)&Ws[row*40 + 8*cg] = v;
            }
            __syncthreads();
            #pragma unroll
            for (int ct = 0; ct < 12; ct++) {
                bf16x8 bfrag = *(const bf16x8*)&Ws[(16*ct + lr)*40 + 8*lg];
                acc[ct] = mfma16(afr[ks], bfrag, acc[ct]);
            }
        }
        if (bias) {
            #pragma unroll
            for (int ct = 0; ct < 12; ct++) {
                float bv = bias[16*ct + lr];
                #pragma unroll
                for (int reg = 0; reg < 4; reg++) acc[ct][reg] += bv;
            }
        }
        if (nrm) {
            #pragma unroll
            for (int h = 0; h < HH; h++) {
                float sc = 1.f;
                if (nrm == 2) sc = __expf(fminf(ls[h], 4.6051702f)) * 1.4426950408889634f;
                #pragma unroll
                for (int reg = 0; reg < 4; reg++) {
                    float ss = acc[2*h][reg]*acc[2*h][reg] + acc[2*h+1][reg]*acc[2*h+1][reg];
                    ss += __shfl_xor(ss, 1); ss += __shfl_xor(ss, 2);
                    ss += __shfl_xor(ss, 4); ss += __shfl_xor(ss, 8);
                    float f = sc / fmaxf(sqrtf(ss), 1e-12f);
                    acc[2*h][reg]   *= f;
                    acc[2*h+1][reg] *= f;
                }
            }
        }
        #pragma unroll
        for (int ct = 0; ct < 12; ct++) {
            int c = 16*ct + lr;
            #pragma unroll
            for (int reg = 0; reg < 4; reg++) {
                int row = m0 + 16*wave + 4*lg + reg;
                D[(size_t)row*DIMC + c] = (__bf16)acc[ct][reg];
            }
        }
    }
}

// ---------------- proj GEMM v3: bf16 A direct, bf16 W staged in LDS, f32 out + bias ----------------
__global__ __launch_bounds__(256) void gemm_proj(
    const __bf16* __restrict__ A, const __bf16* __restrict__ W,
    const float* __restrict__ bias, float* __restrict__ D)
{
    __shared__ __bf16 Ws[192*40];
    int m0 = blockIdx.x * 64;
    int t  = threadIdx.x;
    int wave = t >> 6, lane = t & 63, lr = lane & 15, lg = lane >> 4;
    int r = m0 + 16*wave + lr;

    bf16x8 afr[6];
    #pragma unroll
    for (int ks = 0; ks < 6; ks++)
        afr[ks] = *(const bf16x8*)(A + (size_t)r*DIMC + 32*ks + 8*lg);

    f32x4 acc[12];
    #pragma unroll
    for (int i = 0; i < 12; i++) acc[i] = (f32x4){0.f,0.f,0.f,0.f};
    for (int ks = 0; ks < 6; ks++) {
        __syncthreads();
        #pragma unroll
        for (int i = 0; i < 3; i++) {
            int c = t + 256*i;
            int row = c >> 2, cg = c & 3;
            uint4 v = *(const uint4*)(W + (size_t)row*DIMC + 32*ks + 8*cg);
            *(uint4*)&Ws[row*40 + 8*cg] = v;
        }
        __syncthreads();
        #pragma unroll
        for (int ct = 0; ct < 12; ct++) {
            bf16x8 bfrag = *(const bf16x8*)&Ws[(16*ct + lr)*40 + 8*lg];
            acc[ct] = mfma16(afr[ks], bfrag, acc[ct]);
        }
    }
    #pragma unroll
    for (int ct = 0; ct < 12; ct++) {
        int c = 16*ct + lr;
        float bv = bias[c];
        #pragma unroll
        for (int reg = 0; reg < 4; reg++) {
            int row = m0 + 16*wave + 4*lg + reg;
            D[(size_t)row*DIMC + c] = acc[ct][reg] + bv;
        }
    }
}

// ---------------- fused attention: 32x32 MFMA, permlane P-redistribution, rolled ks ----------------
// QK: S = mfma32(K, Q): lane holds col q=lane&31, rows m_off=(reg&3)+8*(reg>>2)+4*hi
// V^T LDS: linear pitch 360 ushorts (180 dwords == 20 mod 32 -> uniform 2/bank on b128 reads)
// XCD swizzle: 3072 blocks % 8 == 0 -> bh = (bid&7)*384 + (bid>>3); each XCD owns a
// contiguous run of b (all 6 heads together) -> Q/K/V rows hit the same per-XCD L2.
#define VT_PITCH 360
__global__ __launch_bounds__(256, 4) void attn_kernel(
    const __bf16* __restrict__ qb, const __bf16* __restrict__ kb, const __bf16* __restrict__ vb,
    const float* __restrict__ R, const unsigned* __restrict__ mbits,
    __bf16* __restrict__ cross)
{
    __shared__ __bf16 VTs[32*VT_PITCH];   // 23040 B

    int bid = blockIdx.x;
    int bh  = (bid & 7) * (BB*HH/8) + (bid >> 3);
    int b  = bh / HH;
    int h  = bh - b*HH;
    int w  = b & 63;
    int t  = threadIdx.x;

    const __bf16* Kb = kb + ((size_t)b*NN)*DIMC + 32*h;
    const __bf16* Vb = vb + ((size_t)b*NN)*DIMC + 32*h;
    const __bf16* Qb = qb + ((size_t)b*NN)*DIMC + 32*h;

    // stage V^T (consecutive threads -> consecutive m)
    for (int idx = t; idx < NN*4; idx += 256) {
        int part = idx / NN;
        int m    = idx - part*NN;
        union { uint4 u; __bf16 e[8]; } vv;
        vv.u = *(const uint4*)(Vb + (size_t)m*DIMC + 8*part);
        #pragma unroll
        for (int j = 0; j < 8; j++) VTs[(8*part + j)*VT_PITCH + m] = vv.e[j];
    }
    for (int idx = t; idx < 32*9; idx += 256) {
        int d = idx / 9, m = NN + (idx - d*9);
        VTs[d*VT_PITCH + m] = (__bf16)0.f;
    }
    __syncthreads();

    int wave = t >> 6, lane = t & 63;
    int l31 = lane & 31, hi = lane >> 5;
    const f32x16 zero16 = {0.f,0.f,0.f,0.f,0.f,0.f,0.f,0.f,0.f,0.f,0.f,0.f,0.f,0.f,0.f,0.f};
    const __bf16* VTl = VTs + (size_t)l31*VT_PITCH;   // per-lane V row base

    for (int p = wave; p < 11; p += 4) {
        int q0 = 32*p;
        int rq = min(q0 + l31, NN-1);
        bf16x8 qf0 = *(const bf16x8*)(Qb + (size_t)rq*DIMC + 8*hi);        // kd 0..15
        bf16x8 qf1 = *(const bf16x8*)(Qb + (size_t)rq*DIMC + 16 + 8*hi);   // kd 16..31
        const float* Rrow = R + ((size_t)h*NN + rq)*352 + 4*hi;
        const unsigned* mp = mbits + ((size_t)(w*NN + rq))*16 + hi*8;
        uint4 mw = *(const uint4*)mp;
        uint2 mx = *(const uint2*)(mp + 4);
        unsigned long long ma = mw.x | ((unsigned long long)mw.y << 32);
        unsigned long long mbq = mw.z | ((unsigned long long)mw.w << 32);
        unsigned long long mc = mx.x | ((unsigned long long)mx.y << 32);

        f32x16 O = zero16;
        float dsum = 0.f;

        // prefetch K rows for ks=0
        bf16x8 kf0 = *(const bf16x8*)(Kb + (size_t)l31*DIMC + 8*hi);
        bf16x8 kf1 = *(const bf16x8*)(Kb + (size_t)l31*DIMC + 16 + 8*hi);

        for (int ks = 0; ks < 11; ks++) {
            // this-iter R loads (consumed after QK MFMAs)
            f32x4 rA = *(const f32x4*)(Rrow + 32*ks);
            f32x4 rB = *(const f32x4*)(Rrow + 32*ks + 8);
            f32x4 rC = *(const f32x4*)(Rrow + 32*ks + 16);
            f32x4 rD = *(const f32x4*)(Rrow + 32*ks + 24);
            // prefetch K for ks+1
            bf16x8 kf0n = kf0, kf1n = kf1;
            if (ks < 10) {
                int krn = min(32*(ks+1) + l31, NN-1);
                kf0n = *(const bf16x8*)(Kb + (size_t)krn*DIMC + 8*hi);
                kf1n = *(const bf16x8*)(Kb + (size_t)krn*DIMC + 16 + 8*hi);
            }

            f32x16 s = mfma32(kf0, qf0, zero16);
            s = mfma32(kf1, qf1, s);

            unsigned bits = (unsigned)(ma & 0xFFFFu);
            ma = (ma >> 16) | (mbq << 48); mbq = (mbq >> 16) | (mc << 48); mc >>= 16;

            float pv[16];
            #pragma unroll
            for (int r = 0; r < 4; r++) {
                pv[r]    = (bits & (1u << r))      ? __builtin_amdgcn_exp2f(s[r])    * rA[r] : 0.f;
                pv[4+r]  = (bits & (1u << (4+r)))  ? __builtin_amdgcn_exp2f(s[4+r])  * rB[r] : 0.f;
                pv[8+r]  = (bits & (1u << (8+r)))  ? __builtin_amdgcn_exp2f(s[8+r])  * rC[r] : 0.f;
                pv[12+r] = (bits & (1u << (12+r))) ? __builtin_amdgcn_exp2f(s[12+r]) * rD[r] : 0.f;
            }
            {
                float t0 = pv[0]+pv[1], t1 = pv[2]+pv[3], t2 = pv[4]+pv[5], t3 = pv[6]+pv[7];
                float t4 = pv[8]+pv[9], t5 = pv[10]+pv[11], t6 = pv[12]+pv[13], t7 = pv[14]+pv[15];
                dsum += ((t0+t1)+(t2+t3)) + ((t4+t5)+(t6+t7));
            }
            // pack + permlane redistribution (C layout -> A layout)
            unsigned w0 = pack2(pv[0],  pv[1]),  w1 = pack2(pv[2],  pv[3]);
            unsigned w2 = pack2(pv[4],  pv[5]),  w3 = pack2(pv[6],  pv[7]);
            unsigned w4 = pack2(pv[8],  pv[9]),  w5 = pack2(pv[10], pv[11]);
            unsigned w6 = pack2(pv[12], pv[13]), w7 = pack2(pv[14], pv[15]);
            pl32_swap(w0, w2); pl32_swap(w1, w3);
            pl32_swap(w4, w6); pl32_swap(w5, w7);
            union { unsigned u[4]; bf16x8 f; } fa, fb;
            fa.u[0] = w0; fa.u[1] = w1; fa.u[2] = w2; fa.u[3] = w3;   // m in [32ks, 32ks+16)
            fb.u[0] = w4; fb.u[1] = w5; fb.u[2] = w6; fb.u[3] = w7;   // m in [32ks+16, 32ks+32)

            bf16x8 v0 = *(const bf16x8*)&VTl[32*ks + 8*hi];
            bf16x8 v1 = *(const bf16x8*)&VTl[32*ks + 16 + 8*hi];
            O = mfma32(fa.f, v0, O);
            O = mfma32(fb.f, v1, O);

            kf0 = kf0n; kf1 = kf1n;
        }

        dsum += __shfl_xor(dsum, 32);
        float dinv = 1.f / dsum;

        #pragma unroll
        for (int r = 0; r < 16; r++) {
            int off = (r & 3) + 8*(r >> 2) + 4*hi;
            float dv = __shfl(dinv, off);
            int qr = q0 + off;
            if (qr < NN)
                cross[((size_t)b*NN + qr)*DIMC + 32*h + l31] = (__bf16)(O[r] * dv);
        }
    }
}

extern "C" void kernel_launch(void* const* d_in, const int* in_sizes, int n_in,
                              void* d_out, int out_size, void* d_ws, size_t ws_size,
                              hipStream_t stream) {
    const float* x           = (const float*)d_in[0];
    const float* y           = (const float*)d_in[1];
    const float* mask        = (const float*)d_in[2];
    const float* qkv1_w      = (const float*)d_in[3];
    const float* qkv2_w      = (const float*)d_in[4];
    const float* v1_bias     = (const float*)d_in[6];
    const float* q2_bias     = (const float*)d_in[7];
    const float* logit_scale = (const float*)d_in[9];
    const float* cpb_w1      = (const float*)d_in[10];
    const float* cpb_b1      = (const float*)d_in[11];
    const float* cpb_w2      = (const float*)d_in[12];
    const float* proj_w      = (const float*)d_in[13];
    const float* proj_b      = (const float*)d_in[14];
    const float* rel_table   = (const float*)d_in[15];
    const int*   rp_index    = (const int*)d_in[16];

    char* ws = (char*)d_ws;
    float*    table  = (float*)(ws + OFF_TABLE);
    float*    R      = (float*)(ws + OFF_R);
    unsigned* mb     = (unsigned*)(ws + OFF_MB);
    __bf16*   q_bf   = (__bf16*)(ws + OFF_QB);
    __bf16*   k_bf   = (__bf16*)(ws + OFF_KB);
    __bf16*   v_bf   = (__bf16*)(ws + OFF_VB);
    __bf16*   crossb = (__bf16*)(ws + OFF_CROSS);
    __bf16*   wbf    = (__bf16*)(ws + OFF_WB);

    __bf16* w_k    = wbf + 192*DIMC;        // qkv1 rows 192..383
    __bf16* w_v    = wbf + 384*DIMC;        // qkv1 rows 384..575
    __bf16* w_q    = wbf + 576*DIMC;        // qkv2 rows 0..191
    __bf16* w_proj = wbf + 1152*DIMC;

    cpb_table_kernel<<<2197, 256, 0, stream>>>(rel_table, cpb_w1, cpb_b1, cpb_w2, table);
    r_kernel<<<(HH*NN*352 + 255)/256, 256, 0, stream>>>(table, rp_index, R);
    mbits2_kernel<<<(64*NN*2 + 255)/256, 256, 0, stream>>>(mask, mb);
    wcvt_kernel<<<(258048/4 + 255)/256, 256, 0, stream>>>(qkv1_w, qkv2_w, proj_w, wbf);
    // x -> k (norm, no bias), v (+v1_bias, no norm)
    gemm_f32in<<<MM/64, 256, 0, stream>>>(x, logit_scale,
                                          w_k, nullptr, 1, k_bf,
                                          w_v, v1_bias, 0, v_bf);
    // y -> q (+q2_bias, norm+scale*log2e)
    gemm_f32in<<<MM/64, 256, 0, stream>>>(y, logit_scale,
                                          w_q, q2_bias, 2, q_bf,
                                          nullptr, nullptr, 0, nullptr);

    attn_kernel<<<BB*HH, 256, 0, stream>>>(q_bf, k_bf, v_bf, R, mb, crossb);

    gemm_proj<<<MM/64, 256, 0, stream>>>(crossb, w_proj, proj_b, (float*)d_out);
}